// Round 4
// baseline (437.038 us; speedup 1.0000x reference)
//
#include <hip/hip_runtime.h>
#include <hip/hip_bf16.h>
#include <math.h>

// Problem constants
#define BB 2
#define TT 512
#define DD 1024
#define HH 16
#define DHH 64
#define EE 8
#define FF 4096
#define NTOK 1024
#define CAP 2560   // >= 2048 + 8*63 rounded up to 64

typedef __attribute__((ext_vector_type(4))) float f32x4;
typedef __attribute__((ext_vector_type(8))) short short8;

__device__ __forceinline__ short f2b(float f) {
    __hip_bfloat16 h = __float2bfloat16(f);
    return *reinterpret_cast<short*>(&h);
}

// async global->LDS, 16B per lane. LDS dest = wave-uniform base + lane*16.
__device__ __forceinline__ void gload16(const short* g, short* l) {
    __builtin_amdgcn_global_load_lds((const __attribute__((address_space(1))) unsigned int*)g,
                                     (__attribute__((address_space(3))) unsigned int*)l,
                                     16, 0, 0);
}

// ---------------- LayerNorm (templated output dtype) ----------------
template <int BF>
__global__ __launch_bounds__(256) void ln_kernel(const float* __restrict__ x,
                                                 const float* __restrict__ s,
                                                 const float* __restrict__ b,
                                                 void* __restrict__ outp) {
    int row = blockIdx.x;
    int tid = threadIdx.x;
    const float* xr = x + (size_t)row * DD;
    float sm = 0.f, sq = 0.f;
    for (int i = tid; i < DD; i += 256) {
        float v = xr[i];
        sm += v; sq += v * v;
    }
    #pragma unroll
    for (int o = 32; o; o >>= 1) {
        sm += __shfl_down(sm, o);
        sq += __shfl_down(sq, o);
    }
    __shared__ float r1[4], r2[4];
    if ((tid & 63) == 0) { r1[tid >> 6] = sm; r2[tid >> 6] = sq; }
    __syncthreads();
    float tot  = r1[0] + r1[1] + r1[2] + r1[3];
    float totq = r2[0] + r2[1] + r2[2] + r2[3];
    float mu  = tot * (1.f / DD);
    float var = totq * (1.f / DD) - mu * mu;
    float inv = rsqrtf(var + 1e-5f);
    for (int i = tid; i < DD; i += 256) {
        float v = (xr[i] - mu) * inv * s[i] + b[i];
        if (BF) ((short*)outp)[(size_t)row * DD + i] = f2b(v);
        else    ((float*)outp)[(size_t)row * DD + i] = v;
    }
}

// ---------------- Transpose + cast f32 [K][N] -> bf16 [N][K], 64x64 tiles ----------------
__global__ __launch_bounds__(256) void transpose_cast(const float* __restrict__ src,
                                                      short* __restrict__ dst,
                                                      int K, int N) {
    __shared__ float t[64][65];
    src += (size_t)blockIdx.z * K * N;
    dst += (size_t)blockIdx.z * K * N;
    int k0 = blockIdx.y * 64, n0 = blockIdx.x * 64;
    int rr = threadIdx.x >> 4;           // 0..15
    int cc = (threadIdx.x & 15) * 4;     // 0..60
    #pragma unroll
    for (int p = 0; p < 4; p++) {
        float4 v = *(const float4*)&src[(size_t)(k0 + rr + p * 16) * N + n0 + cc];
        t[rr + p * 16][cc]     = v.x;
        t[rr + p * 16][cc + 1] = v.y;
        t[rr + p * 16][cc + 2] = v.z;
        t[rr + p * 16][cc + 3] = v.w;
    }
    __syncthreads();
    #pragma unroll
    for (int p = 0; p < 4; p++) {
        int n = rr + p * 16;
        short4 o;
        o.x = f2b(t[cc][n]); o.y = f2b(t[cc + 1][n]);
        o.z = f2b(t[cc + 2][n]); o.w = f2b(t[cc + 3][n]);
        *(short4*)&dst[(size_t)(n0 + n) * K + k0 + cc] = o;
    }
}

// ---------------- bf16 -> bf16 transpose V[t][d] -> VT[d][t] per (b,h) ----------------
__global__ __launch_bounds__(256) void v_transpose(const short* __restrict__ Vb,
                                                   short* __restrict__ VTb) {
    __shared__ short t[32][33];
    int bh = blockIdx.z;
    const short* src = Vb + (size_t)bh * TT * DHH;
    short* dst = VTb + (size_t)bh * DHH * TT;
    int t0 = blockIdx.x * 32, d0 = blockIdx.y * 32;
    int tx = threadIdx.x & 31, ty = threadIdx.x >> 5;
    #pragma unroll
    for (int p = 0; p < 4; p++)
        t[ty + p * 8][tx] = src[(size_t)(t0 + ty + p * 8) * DHH + d0 + tx];
    __syncthreads();
    #pragma unroll
    for (int p = 0; p < 4; p++)
        dst[(size_t)(d0 + ty + p * 8) * TT + t0 + tx] = t[tx][ty + p * 8];
}

// ================= WIDE GEMM CORE: 64(M) x 128(N) tile, BK=64, 4 waves =================
// A: [M][K] bf16 row-major, B: [N][K] bf16 row-major.
// Wave (wr=wave>>1, wc=wave&1) computes 32x64: acc[2][4] of 16x16 frags.
// LDS: As 64x64 (8KB), Bs 128x64 (16KB). Swizzle: 16B slot ^= (row&7), inverse-swizzled
// global source + swizzled ds_read (rule #21).
__device__ __forceinline__ void gemm_loop_w(const short* __restrict__ A,
                                            const short* __restrict__ B,
                                            int K, short* As, short* Bs,
                                            f32x4 acc[2][4], int m0, int n0, int tid) {
    int wave = tid >> 6, lane = tid & 63;
    int wr = wave >> 1, wc = wave & 1;
    int lrow = lane & 15, lk = lane >> 4;
    int sr = tid >> 3, ss = tid & 7;
    int sswz = (ss ^ (sr & 7)) * 8;
    const short* Ag0 = A + (size_t)(m0 + sr) * K + sswz;
    const short* Ag1 = A + (size_t)(m0 + sr + 32) * K + sswz;
    const short* Bg0 = B + (size_t)(n0 + sr) * K + sswz;
    const short* Bg1 = B + (size_t)(n0 + sr + 32) * K + sswz;
    const short* Bg2 = B + (size_t)(n0 + sr + 64) * K + sswz;
    const short* Bg3 = B + (size_t)(n0 + sr + 96) * K + sswz;
    short* lA0 = As + wave * 512;
    short* lA1 = As + 2048 + wave * 512;
    short* lB0 = Bs + wave * 512;
    short* lB1 = Bs + 2048 + wave * 512;
    short* lB2 = Bs + 4096 + wave * 512;
    short* lB3 = Bs + 6144 + wave * 512;
    for (int k0 = 0; k0 < K; k0 += 64) {
        gload16(Ag0 + k0, lA0);
        gload16(Ag1 + k0, lA1);
        gload16(Bg0 + k0, lB0);
        gload16(Bg1 + k0, lB1);
        gload16(Bg2 + k0, lB2);
        gload16(Bg3 + k0, lB3);
        __syncthreads();
        #pragma unroll
        for (int kk = 0; kk < 2; kk++) {
            int slot = kk * 4 + lk;
            short8 a[2], b[4];
            #pragma unroll
            for (int i = 0; i < 2; i++) {
                int row = wr * 32 + i * 16 + lrow;
                uint4 v = ((const uint4*)As)[row * 8 + (slot ^ (row & 7))];
                a[i] = *(short8*)&v;
            }
            #pragma unroll
            for (int j = 0; j < 4; j++) {
                int row = wc * 64 + j * 16 + lrow;
                uint4 v = ((const uint4*)Bs)[row * 8 + (slot ^ (row & 7))];
                b[j] = *(short8*)&v;
            }
            #pragma unroll
            for (int i = 0; i < 2; i++)
                #pragma unroll
                for (int j = 0; j < 4; j++)
                    acc[i][j] = __builtin_amdgcn_mfma_f32_16x16x32_bf16(a[i], b[j], acc[i][j], 0, 0, 0);
        }
        __syncthreads();
    }
}

// ---------------- 64x64 core (kept for PV, N=64) ----------------
__device__ __forceinline__ void gemm_loop64(const short* __restrict__ A,
                                            const short* __restrict__ B,
                                            int K, short* As, short* Bs,
                                            f32x4 acc[2][2], int m0, int n0, int tid) {
    int wave = tid >> 6, lane = tid & 63;
    int wr = wave >> 1, wc = wave & 1;
    int lrow = lane & 15, lk = lane >> 4;
    int sr = tid >> 3, ss = tid & 7;
    int sswz = (ss ^ (sr & 7)) * 8;
    const short* Ag0 = A + (size_t)(m0 + sr) * K + sswz;
    const short* Ag1 = A + (size_t)(m0 + sr + 32) * K + sswz;
    const short* Bg0 = B + (size_t)(n0 + sr) * K + sswz;
    const short* Bg1 = B + (size_t)(n0 + sr + 32) * K + sswz;
    short* lA0 = As + wave * 512;
    short* lA1 = As + 2048 + wave * 512;
    short* lB0 = Bs + wave * 512;
    short* lB1 = Bs + 2048 + wave * 512;
    for (int k0 = 0; k0 < K; k0 += 64) {
        gload16(Ag0 + k0, lA0);
        gload16(Ag1 + k0, lA1);
        gload16(Bg0 + k0, lB0);
        gload16(Bg1 + k0, lB1);
        __syncthreads();
        #pragma unroll
        for (int kk = 0; kk < 2; kk++) {
            int slot = kk * 4 + lk;
            short8 a[2], b[2];
            #pragma unroll
            for (int i = 0; i < 2; i++) {
                int row = wr * 32 + i * 16 + lrow;
                uint4 v = ((const uint4*)As)[row * 8 + (slot ^ (row & 7))];
                a[i] = *(short8*)&v;
            }
            #pragma unroll
            for (int j = 0; j < 2; j++) {
                int row = wc * 32 + j * 16 + lrow;
                uint4 v = ((const uint4*)Bs)[row * 8 + (slot ^ (row & 7))];
                b[j] = *(short8*)&v;
            }
            #pragma unroll
            for (int i = 0; i < 2; i++)
                #pragma unroll
                for (int j = 0; j < 2; j++)
                    acc[i][j] = __builtin_amdgcn_mfma_f32_16x16x32_bf16(a[i], b[j], acc[i][j], 0, 0, 0);
        }
        __syncthreads();
    }
}

// ---------------- Generic wide GEMM: MODE 0: C=A@W^T+bias ; MODE 1: C=res+A@W^T+bias ----------------
template <int MODE>
__global__ __launch_bounds__(256) void gemm_mfma(const short* __restrict__ A,
                                                 const short* __restrict__ Bw,
                                                 const float* __restrict__ bias,
                                                 const float* __restrict__ res,
                                                 float* __restrict__ C,
                                                 int N, int K) {
    __shared__ short As[4096];
    __shared__ short Bs[8192];
    int tid = threadIdx.x;
    int m0 = blockIdx.y * 64, n0 = blockIdx.x * 128;
    f32x4 acc[2][4] = {};
    gemm_loop_w(A, Bw, K, As, Bs, acc, m0, n0, tid);
    int wave = tid >> 6, lane = tid & 63;
    int wr = wave >> 1, wc = wave & 1;
    int lrow = lane & 15, lk = lane >> 4;
    #pragma unroll
    for (int i = 0; i < 2; i++) {
        #pragma unroll
        for (int j = 0; j < 4; j++) {
            int col = n0 + wc * 64 + j * 16 + lrow;
            float bv = bias[col];
            #pragma unroll
            for (int r = 0; r < 4; r++) {
                int row = m0 + wr * 32 + i * 16 + lk * 4 + r;
                float v = acc[i][j][r] + bv;
                if (MODE == 1) v += res[(size_t)row * N + col];
                C[(size_t)row * N + col] = v;
            }
        }
    }
}

// ---------------- QKV GEMM: bf16 out, head-major split ----------------
__global__ __launch_bounds__(256) void qkv_mfma(const short* __restrict__ A,
                                                const short* __restrict__ Bw,
                                                const float* __restrict__ bias,
                                                short* __restrict__ Qb,
                                                short* __restrict__ Kb,
                                                short* __restrict__ Vb) {
    __shared__ short As[4096];
    __shared__ short Bs[8192];
    int tid = threadIdx.x;
    int m0 = blockIdx.y * 64, n0 = blockIdx.x * 128;
    f32x4 acc[2][4] = {};
    gemm_loop_w(A, Bw, DD, As, Bs, acc, m0, n0, tid);
    int wave = tid >> 6, lane = tid & 63;
    int wr = wave >> 1, wc = wave & 1;
    int lrow = lane & 15, lk = lane >> 4;
    #pragma unroll
    for (int i = 0; i < 2; i++) {
        #pragma unroll
        for (int j = 0; j < 4; j++) {
            int col = n0 + wc * 64 + j * 16 + lrow;    // 0..3071
            int part = col >> 10;
            int rem = col & 1023;
            int h = rem >> 6, d = rem & 63;
            short* dst = (part == 0) ? Qb : ((part == 1) ? Kb : Vb);
            float bv = bias[col];
            #pragma unroll
            for (int r = 0; r < 4; r++) {
                int row = m0 + wr * 32 + i * 16 + lk * 4 + r;   // token
                int b = row >> 9, t = row & (TT - 1);
                dst[(((size_t)(b * HH + h)) * TT + t) * DHH + d] = f2b(acc[i][j][r] + bv);
            }
        }
    }
}

// ---------------- scores = Q @ K^T per (b,h), f32 out ----------------
__global__ __launch_bounds__(256) void scores_mfma(const short* __restrict__ Qb,
                                                   const short* __restrict__ Kb,
                                                   float* __restrict__ S) {
    __shared__ short As[4096];
    __shared__ short Bs[8192];
    int tid = threadIdx.x;
    int bh = blockIdx.z;
    const short* A = Qb + (size_t)bh * TT * DHH;
    const short* B = Kb + (size_t)bh * TT * DHH;
    float* Sp = S + (size_t)bh * TT * TT;
    int m0 = blockIdx.y * 64, n0 = blockIdx.x * 128;
    f32x4 acc[2][4] = {};
    gemm_loop_w(A, B, DHH, As, Bs, acc, m0, n0, tid);
    int wave = tid >> 6, lane = tid & 63;
    int wr = wave >> 1, wc = wave & 1;
    int lrow = lane & 15, lk = lane >> 4;
    #pragma unroll
    for (int i = 0; i < 2; i++)
        #pragma unroll
        for (int j = 0; j < 4; j++) {
            int col = n0 + wc * 64 + j * 16 + lrow;
            #pragma unroll
            for (int r = 0; r < 4; r++) {
                int row = m0 + wr * 32 + i * 16 + lk * 4 + r;
                Sp[(size_t)row * TT + col] = acc[i][j][r];
            }
        }
}

// ---------------- softmax rows: P = softmax(S/8 + rel_bias), bf16 out ----------------
__global__ __launch_bounds__(256) void softmax_kernel(const float* __restrict__ S,
                                                      const float* __restrict__ rel_bias,
                                                      short* __restrict__ P) {
    int row = blockIdx.x * 4 + (threadIdx.x >> 6);   // (b*H+h)*T + t
    int lane = threadIdx.x & 63;
    int t = row & (TT - 1), h = (row >> 9) & (HH - 1);
    const float* Sr = S + (size_t)row * TT;
    const float* br = rel_bias + h * (2 * TT - 1) + (TT - 1) - t;
    float v[8];
    float mx = -1e30f;
    #pragma unroll
    for (int i = 0; i < 8; i++) {
        int s = lane + i * 64;
        v[i] = Sr[s] * 0.125f + br[s];
        mx = fmaxf(mx, v[i]);
    }
    #pragma unroll
    for (int o = 32; o; o >>= 1) mx = fmaxf(mx, __shfl_xor(mx, o));
    float sum = 0.f;
    #pragma unroll
    for (int i = 0; i < 8; i++) { v[i] = expf(v[i] - mx); sum += v[i]; }
    #pragma unroll
    for (int o = 32; o; o >>= 1) sum += __shfl_xor(sum, o);
    float inv = 1.f / sum;
    #pragma unroll
    for (int i = 0; i < 8; i++)
        P[(size_t)row * TT + lane + i * 64] = f2b(v[i] * inv);
}

// ---------------- ctx = P @ V^T per (b,h), bf16 out into [t][h*64+d] ----------------
__global__ __launch_bounds__(256) void pv_mfma(const short* __restrict__ P,
                                               const short* __restrict__ VTb,
                                               short* __restrict__ ctxb) {
    __shared__ short As[4096];
    __shared__ short Bs[4096];
    int tid = threadIdx.x;
    int bh = blockIdx.z;
    int h = bh & (HH - 1), b = bh >> 4;
    const short* A = P + (size_t)bh * TT * TT;
    const short* B = VTb + (size_t)bh * DHH * TT;
    int m0 = blockIdx.y * 64;
    f32x4 acc[2][2] = {};
    gemm_loop64(A, B, TT, As, Bs, acc, m0, 0, tid);
    int wave = tid >> 6, lane = tid & 63;
    int wr = wave >> 1, wc = wave & 1;
    int lrow = lane & 15, lk = lane >> 4;
    #pragma unroll
    for (int i = 0; i < 2; i++)
        #pragma unroll
        for (int j = 0; j < 2; j++) {
            int d = wc * 32 + j * 16 + lrow;
            #pragma unroll
            for (int r = 0; r < 4; r++) {
                int row = m0 + wr * 32 + i * 16 + lk * 4 + r;   // t
                ctxb[((size_t)(b * TT + row)) * DD + h * DHH + d] = f2b(acc[i][j][r]);
            }
        }
}

// ---------------- MoE GEMM1: hid = gelu(Ag @ w1t[e]^T + b1[e]) (bf16 out) ----------------
__global__ __launch_bounds__(256) void moe_gemm1_mfma(const short* __restrict__ Ag,
                                                      const short* __restrict__ W1t,
                                                      const float* __restrict__ b1,
                                                      const int* __restrict__ counts,
                                                      const int* __restrict__ offs,
                                                      short* __restrict__ hid) {
    int e = blockIdx.y >> 5, tile = blockIdx.y & 31;
    int cnt = counts[e];
    int pcnt = (cnt + 63) & ~63;
    int row0 = tile * 64;
    if (row0 >= pcnt) return;
    int base = offs[e];
    const short* A  = Ag + (size_t)base * DD;
    const short* Bw = W1t + (size_t)e * FF * DD;   // [F][D]
    __shared__ short As[4096];
    __shared__ short Bs[8192];
    int tid = threadIdx.x;
    int n0 = blockIdx.x * 128;
    f32x4 acc[2][4] = {};
    gemm_loop_w(A, Bw, DD, As, Bs, acc, row0, n0, tid);
    int wave = tid >> 6, lane = tid & 63;
    int wr = wave >> 1, wc = wave & 1;
    int lrow = lane & 15, lk = lane >> 4;
    #pragma unroll
    for (int i = 0; i < 2; i++) {
        #pragma unroll
        for (int j = 0; j < 4; j++) {
            int col = n0 + wc * 64 + j * 16 + lrow;
            float bv = b1[e * FF + col];
            #pragma unroll
            for (int r = 0; r < 4; r++) {
                int row = row0 + wr * 32 + i * 16 + lk * 4 + r;
                float v = acc[i][j][r] + bv;
                float u = 0.7978845608028654f * (v + 0.044715f * v * v * v);
                float g = 0.5f * v * (1.f + tanhf(u));
                hid[(size_t)(base + row) * FF + col] = f2b(g);
            }
        }
    }
}

// ---------------- MoE GEMM2: pair_out = gate * (hid @ w2t[e]^T + b2[e]) ----------------
__global__ __launch_bounds__(256) void moe_gemm2_mfma(const short* __restrict__ hid,
                                                      const short* __restrict__ W2t,
                                                      const float* __restrict__ b2,
                                                      const float* __restrict__ pair_gate,
                                                      const int* __restrict__ counts,
                                                      const int* __restrict__ offs,
                                                      float* __restrict__ pair_out) {
    int e = blockIdx.y >> 5, tile = blockIdx.y & 31;
    int cnt = counts[e];
    int pcnt = (cnt + 63) & ~63;
    int row0 = tile * 64;
    if (row0 >= pcnt) return;
    int base = offs[e];
    const short* A  = hid + (size_t)base * FF;
    const short* Bw = W2t + (size_t)e * DD * FF;   // [D][F]
    __shared__ short As[4096];
    __shared__ short Bs[8192];
    int tid = threadIdx.x;
    int n0 = blockIdx.x * 128;
    f32x4 acc[2][4] = {};
    gemm_loop_w(A, Bw, FF, As, Bs, acc, row0, n0, tid);
    int wave = tid >> 6, lane = tid & 63;
    int wr = wave >> 1, wc = wave & 1;
    int lrow = lane & 15, lk = lane >> 4;
    #pragma unroll
    for (int i = 0; i < 2; i++) {
        #pragma unroll
        for (int j = 0; j < 4; j++) {
            int col = n0 + wc * 64 + j * 16 + lrow;
            float bv = b2[e * DD + col];
            #pragma unroll
            for (int r = 0; r < 4; r++) {
                int row = row0 + wr * 32 + i * 16 + lk * 4 + r;
                float g = pair_gate[base + row];
                pair_out[(size_t)(base + row) * DD + col] = g * (acc[i][j][r] + bv);
            }
        }
    }
}

// ---------------- text projection ----------------
__global__ __launch_bounds__(256) void txt_kernel(const float* __restrict__ ts,
                                                  const float* __restrict__ w,
                                                  const float* __restrict__ bias,
                                                  float* __restrict__ out) {
    int gid = blockIdx.x * 256 + threadIdx.x;   // 0..B*D-1
    int b = gid >> 10;
    int n = gid & (DD - 1);
    float acc = 0.f;
    for (int d = 0; d < DD; d++) acc += ts[b * DD + d] * w[(size_t)d * DD + n];
    out[gid] = acc + bias[n];
}

// ---------------- router ----------------
__global__ __launch_bounds__(256) void router_kernel(const float* __restrict__ h2,
                                                     const float* __restrict__ txt,
                                                     const float* __restrict__ w_r,
                                                     const float* __restrict__ b_r,
                                                     float* __restrict__ probs,
                                                     float* __restrict__ gates,
                                                     int* __restrict__ counts) {
    int row = blockIdx.x;       // token
    int b = row >> 9;
    int tid = threadIdx.x;
    float acc[EE] = {};
    for (int d = tid; d < DD; d += 256) {
        float r = h2[(size_t)row * DD + d] + txt[b * DD + d];
        #pragma unroll
        for (int e = 0; e < EE; e++) acc[e] += r * w_r[d * EE + e];
    }
    #pragma unroll
    for (int e = 0; e < EE; e++)
        #pragma unroll
        for (int o = 32; o; o >>= 1) acc[e] += __shfl_down(acc[e], o);
    __shared__ float lds[4][EE];
    int lane = tid & 63, w = tid >> 6;
    if (lane == 0)
        for (int e = 0; e < EE; e++) lds[w][e] = acc[e];
    __syncthreads();
    if (tid == 0) {
        float lg[EE], p[EE];
        float mx = -1e30f;
        for (int e = 0; e < EE; e++) {
            lg[e] = lds[0][e] + lds[1][e] + lds[2][e] + lds[3][e] + b_r[e];
            mx = fmaxf(mx, lg[e]);
        }
        float sum = 0.f;
        for (int e = 0; e < EE; e++) { p[e] = expf(lg[e] - mx); sum += p[e]; }
        float invs = 1.f / sum;
        for (int e = 0; e < EE; e++) { p[e] *= invs; probs[row * EE + e] = p[e]; }
        int i1 = 0;
        for (int e = 1; e < EE; e++) if (p[e] > p[i1]) i1 = e;
        int i2 = (i1 == 0) ? 1 : 0;
        for (int e = 0; e < EE; e++) if (e != i1 && p[e] > p[i2]) i2 = e;
        float gs = p[i1] + p[i2];
        for (int e = 0; e < EE; e++) gates[row * EE + e] = 0.f;
        gates[row * EE + i1] = p[i1] / gs;
        gates[row * EE + i2] = p[i2] / gs;
        atomicAdd(&counts[i1], 1);
        atomicAdd(&counts[i2], 1);
    }
}

// ---------------- expert offsets (64-aligned segments) ----------------
__global__ void offs_kernel(const int* __restrict__ counts, int* __restrict__ offs) {
    if (threadIdx.x == 0) {
        int acc = 0;
        for (int e = 0; e < EE; e++) { offs[e] = acc; acc += (counts[e] + 63) & ~63; }
    }
}

// ---------------- scatter tokens into per-expert lists ----------------
__global__ __launch_bounds__(256) void scatter_kernel(const float* __restrict__ gates,
                                                      const int* __restrict__ offs,
                                                      int* __restrict__ fill,
                                                      int* __restrict__ tok_pos,
                                                      float* __restrict__ pair_gate) {
    int t = blockIdx.x * 256 + threadIdx.x;   // token
    if (t >= NTOK) return;
    int slot = 0;
    for (int e = 0; e < EE; e++) {
        float g = gates[t * EE + e];
        if (g > 0.f) {
            int pos = offs[e] + atomicAdd(&fill[e], 1);
            tok_pos[t * 2 + slot] = pos;
            pair_gate[pos] = g;
            slot++;
        }
    }
}

// ---------------- gather tokens (h2 f32 -> bf16 rows of Ag) ----------------
__global__ __launch_bounds__(256) void gather_tokens(const float* __restrict__ h2,
                                                     const int* __restrict__ tok_pos,
                                                     short* __restrict__ Ag) {
    int i = blockIdx.x;          // 0..2047  (t = i>>1)
    int pos = tok_pos[i];
    int t = i >> 1;
    int d = threadIdx.x * 4;
    #pragma unroll
    for (int k = 0; k < 4; k++)
        Ag[(size_t)pos * DD + d + k] = f2b(h2[(size_t)t * DD + d + k]);
}

// ---------------- diag = mean(probs) ----------------
__global__ __launch_bounds__(256) void diag_kernel(const float* __restrict__ probs,
                                                   float* __restrict__ out) {
    int e = blockIdx.x;
    int tid = threadIdx.x;
    float s = 0.f;
    for (int t = tid; t < NTOK; t += 256) s += probs[t * EE + e];
    #pragma unroll
    for (int o = 32; o; o >>= 1) s += __shfl_down(s, o);
    __shared__ float red[4];
    if ((tid & 63) == 0) red[tid >> 6] = s;
    __syncthreads();
    if (tid == 0) out[e] = (red[0] + red[1] + red[2] + red[3]) * (1.f / NTOK);
}

// ---------------- final: out += pair_out[posA] + pair_out[posB] ----------------
__global__ __launch_bounds__(256) void finaladd_kernel(float* __restrict__ out,
                                                       const float* __restrict__ pair_out,
                                                       const int* __restrict__ tok_pos) {
    int t = blockIdx.x;
    int pA = tok_pos[2 * t], pB = tok_pos[2 * t + 1];
    int d = threadIdx.x * 4;
    float4 a = *(const float4*)&out[(size_t)t * DD + d];
    float4 u = *(const float4*)&pair_out[(size_t)pA * DD + d];
    float4 v = *(const float4*)&pair_out[(size_t)pB * DD + d];
    a.x += u.x + v.x; a.y += u.y + v.y; a.z += u.z + v.z; a.w += u.w + v.w;
    *(float4*)&out[(size_t)t * DD + d] = a;
}

extern "C" void kernel_launch(void* const* d_in, const int* in_sizes, int n_in,
                              void* d_out, int out_size, void* d_ws, size_t ws_size,
                              hipStream_t stream) {
    const float* x          = (const float*)d_in[0];
    const float* text_state = (const float*)d_in[1];
    const float* ln1_s      = (const float*)d_in[2];
    const float* ln1_b      = (const float*)d_in[3];
    const float* w_qkv      = (const float*)d_in[4];
    const float* b_qkv      = (const float*)d_in[5];
    const float* w_o        = (const float*)d_in[6];
    const float* b_o        = (const float*)d_in[7];
    const float* rel_bias   = (const float*)d_in[8];
    const float* ln2_s      = (const float*)d_in[9];
    const float* ln2_b      = (const float*)d_in[10];
    const float* w_txt      = (const float*)d_in[11];
    const float* b_txt      = (const float*)d_in[12];
    const float* w_r        = (const float*)d_in[13];
    const float* b_r        = (const float*)d_in[14];
    const float* w1         = (const float*)d_in[15];
    const float* b1         = (const float*)d_in[16];
    const float* w2         = (const float*)d_in[17];
    const float* b2         = (const float*)d_in[18];

    float* out = (float*)d_out;   // [NTOK*D] then [E] diag

    // ---- workspace layout ----
    char* p = (char*)d_ws;
    auto alloc = [&](size_t bytes) { char* r = p; p += (bytes + 255) & ~(size_t)255; return r; };
    short* h1b      = (short*)alloc((size_t)NTOK * DD * 2);
    short* Qb       = (short*)alloc((size_t)NTOK * DD * 2);
    short* Kb       = (short*)alloc((size_t)NTOK * DD * 2);
    short* Vb       = (short*)alloc((size_t)NTOK * DD * 2);
    short* VTb      = (short*)alloc((size_t)NTOK * DD * 2);
    // region1: S (f32 33.5MB) -> later Ag(5MB)+hid(20MB)
    char*  region1  = alloc((size_t)BB * HH * TT * TT * 4);
    // region2: P (bf16 16.8MB) -> later pair_out(10MB)
    char*  region2  = alloc((size_t)BB * HH * TT * TT * 2);
    short* ctxb     = (short*)alloc((size_t)NTOK * DD * 2);
    float* h2       = (float*)alloc((size_t)NTOK * DD * 4);
    float* txt      = (float*)alloc((size_t)BB * DD * 4);
    float* probs    = (float*)alloc((size_t)NTOK * EE * 4);
    float* gates    = (float*)alloc((size_t)NTOK * EE * 4);
    float* pair_gate= (float*)alloc((size_t)CAP * 4);
    int*   counts   = (int*)alloc(8 * 4);
    int*   fill     = (int*)alloc(8 * 4);
    int*   offs     = (int*)alloc(8 * 4);
    int*   tok_pos  = (int*)alloc((size_t)NTOK * 2 * 4);
    short* wqkvT    = (short*)alloc((size_t)3 * DD * DD * 2);        // [3D][D]
    short* woT      = (short*)alloc((size_t)DD * DD * 2);            // [D][D]
    short* w1T      = (short*)alloc((size_t)EE * FF * DD * 2);       // [E][F][D]
    short* w2T      = (short*)alloc((size_t)EE * DD * FF * 2);       // [E][D][F]

    float* S        = (float*)region1;
    short* P        = (short*)region2;
    short* Ag       = (short*)region1;                               // after attn
    short* hid      = (short*)(region1 + ((size_t)CAP * DD * 2 + 255 & ~(size_t)255));
    float* pair_out = (float*)region2;                               // after attn

    // ---- weight prep ----
    transpose_cast<<<dim3(3 * DD / 64, DD / 64, 1), 256, 0, stream>>>(w_qkv, wqkvT, DD, 3 * DD);
    transpose_cast<<<dim3(DD / 64, DD / 64, 1), 256, 0, stream>>>(w_o, woT, DD, DD);
    transpose_cast<<<dim3(FF / 64, DD / 64, EE), 256, 0, stream>>>(w1, w1T, DD, FF);
    transpose_cast<<<dim3(DD / 64, FF / 64, EE), 256, 0, stream>>>(w2, w2T, FF, DD);

    // ---- 1. LN1 (bf16 out) ----
    ln_kernel<1><<<NTOK, 256, 0, stream>>>(x, ln1_s, ln1_b, h1b);
    // ---- 2. QKV GEMM -> bf16 head-major Q/K/V ----
    qkv_mfma<<<dim3(3 * DD / 128, NTOK / 64), 256, 0, stream>>>(h1b, wqkvT, b_qkv, Qb, Kb, Vb);
    // ---- 3. V transpose per (b,h) ----
    v_transpose<<<dim3(TT / 32, DHH / 32, BB * HH), 256, 0, stream>>>(Vb, VTb);
    // ---- 4. scores ----
    scores_mfma<<<dim3(TT / 128, TT / 64, BB * HH), 256, 0, stream>>>(Qb, Kb, S);
    // ---- 5. softmax (scale + rel bias folded) ----
    softmax_kernel<<<BB * HH * TT / 4, 256, 0, stream>>>(S, rel_bias, P);
    // ---- 6. ctx = P @ V^T ----
    pv_mfma<<<dim3(1, TT / 64, BB * HH), 256, 0, stream>>>(P, VTb, ctxb);
    // ---- 7. x1 = x + ctx @ w_o + b_o -> out ----
    gemm_mfma<1><<<dim3(DD / 128, NTOK / 64), 256, 0, stream>>>(ctxb, woT, b_o, x, out, DD, DD);
    // ---- 8. LN2 (f32 out) ----
    ln_kernel<0><<<NTOK, 256, 0, stream>>>(out, ln2_s, ln2_b, h2);
    // ---- 9. text projection ----
    txt_kernel<<<(BB * DD) / 256, 256, 0, stream>>>(text_state, w_txt, b_txt, txt);
    // ---- 10. zero scratch ----
    hipMemsetAsync(counts, 0, 8 * 4, stream);
    hipMemsetAsync(fill, 0, 8 * 4, stream);
    hipMemsetAsync(Ag, 0, (size_t)CAP * DD * 2, stream);
    // ---- 11. router ----
    router_kernel<<<NTOK, 256, 0, stream>>>(h2, txt, w_r, b_r, probs, gates, counts);
    // ---- 12. aligned offsets ----
    offs_kernel<<<1, 64, 0, stream>>>(counts, offs);
    // ---- 13. scatter ----
    scatter_kernel<<<NTOK / 256, 256, 0, stream>>>(gates, offs, fill, tok_pos, pair_gate);
    // ---- 14. gather rows into Ag (bf16) ----
    gather_tokens<<<NTOK * 2, 256, 0, stream>>>(h2, tok_pos, Ag);
    // ---- 15. diag ----
    diag_kernel<<<EE, 256, 0, stream>>>(probs, out + (size_t)NTOK * DD);
    // ---- 16. MoE GEMM1 ----
    moe_gemm1_mfma<<<dim3(FF / 128, EE * 32), 256, 0, stream>>>(Ag, w1T, b1, counts, offs, hid);
    // ---- 17. MoE GEMM2 ----
    moe_gemm2_mfma<<<dim3(DD / 128, EE * 32), 256, 0, stream>>>(hid, w2T, b2, pair_gate, counts, offs, pair_out);
    // ---- 18. final add ----
    finaladd_kernel<<<NTOK, 256, 0, stream>>>(out, pair_out, tok_pos);
}

// Round 5
// 408.170 us; speedup vs baseline: 1.0707x; 1.0707x over previous
//
#include <hip/hip_runtime.h>
#include <hip/hip_bf16.h>
#include <math.h>

// Problem constants
#define BB 2
#define TT 512
#define DD 1024
#define HH 16
#define DHH 64
#define EE 8
#define FF 4096
#define NTOK 1024
#define CAP 2560   // >= 2048 + 8*63 rounded up to 64
#define SPL 2      // split-K factor for moe_gemm2

typedef __attribute__((ext_vector_type(4))) float f32x4;
typedef __attribute__((ext_vector_type(8))) short short8;

__device__ __forceinline__ short f2b(float f) {
    __hip_bfloat16 h = __float2bfloat16(f);
    return *reinterpret_cast<short*>(&h);
}
__device__ __forceinline__ float b2f(short s) {
    __hip_bfloat16 h = *reinterpret_cast<__hip_bfloat16*>(&s);
    return __bfloat162float(h);
}

// async global->LDS, 16B per lane. LDS dest = wave-uniform base + lane*16.
__device__ __forceinline__ void gload16(const short* g, short* l) {
    __builtin_amdgcn_global_load_lds((const __attribute__((address_space(1))) unsigned int*)g,
                                     (__attribute__((address_space(3))) unsigned int*)l,
                                     16, 0, 0);
}

// ---------------- LayerNorm (templated output dtype) ----------------
template <int BF>
__global__ __launch_bounds__(256) void ln_kernel(const float* __restrict__ x,
                                                 const float* __restrict__ s,
                                                 const float* __restrict__ b,
                                                 void* __restrict__ outp) {
    int row = blockIdx.x;
    int tid = threadIdx.x;
    const float* xr = x + (size_t)row * DD;
    float sm = 0.f, sq = 0.f;
    for (int i = tid; i < DD; i += 256) {
        float v = xr[i];
        sm += v; sq += v * v;
    }
    #pragma unroll
    for (int o = 32; o; o >>= 1) {
        sm += __shfl_down(sm, o);
        sq += __shfl_down(sq, o);
    }
    __shared__ float r1[4], r2[4];
    if ((tid & 63) == 0) { r1[tid >> 6] = sm; r2[tid >> 6] = sq; }
    __syncthreads();
    float tot  = r1[0] + r1[1] + r1[2] + r1[3];
    float totq = r2[0] + r2[1] + r2[2] + r2[3];
    float mu  = tot * (1.f / DD);
    float var = totq * (1.f / DD) - mu * mu;
    float inv = rsqrtf(var + 1e-5f);
    for (int i = tid; i < DD; i += 256) {
        float v = (xr[i] - mu) * inv * s[i] + b[i];
        if (BF) ((short*)outp)[(size_t)row * DD + i] = f2b(v);
        else    ((float*)outp)[(size_t)row * DD + i] = v;
    }
}

// ---------------- Transpose + cast f32 [K][N] -> bf16 [N][K], 64x64 tiles ----------------
__global__ __launch_bounds__(256) void transpose_cast(const float* __restrict__ src,
                                                      short* __restrict__ dst,
                                                      int K, int N) {
    __shared__ float t[64][65];
    src += (size_t)blockIdx.z * K * N;
    dst += (size_t)blockIdx.z * K * N;
    int k0 = blockIdx.y * 64, n0 = blockIdx.x * 64;
    int rr = threadIdx.x >> 4;           // 0..15
    int cc = (threadIdx.x & 15) * 4;     // 0..60
    #pragma unroll
    for (int p = 0; p < 4; p++) {
        float4 v = *(const float4*)&src[(size_t)(k0 + rr + p * 16) * N + n0 + cc];
        t[rr + p * 16][cc]     = v.x;
        t[rr + p * 16][cc + 1] = v.y;
        t[rr + p * 16][cc + 2] = v.z;
        t[rr + p * 16][cc + 3] = v.w;
    }
    __syncthreads();
    #pragma unroll
    for (int p = 0; p < 4; p++) {
        int n = rr + p * 16;
        short4 o;
        o.x = f2b(t[cc][n]); o.y = f2b(t[cc + 1][n]);
        o.z = f2b(t[cc + 2][n]); o.w = f2b(t[cc + 3][n]);
        *(short4*)&dst[(size_t)(n0 + n) * K + k0 + cc] = o;
    }
}

// ---------------- bf16 -> bf16 transpose V[t][d] -> VT[d][t] per (b,h) ----------------
__global__ __launch_bounds__(256) void v_transpose(const short* __restrict__ Vb,
                                                   short* __restrict__ VTb) {
    __shared__ short t[32][33];
    int bh = blockIdx.z;
    const short* src = Vb + (size_t)bh * TT * DHH;
    short* dst = VTb + (size_t)bh * DHH * TT;
    int t0 = blockIdx.x * 32, d0 = blockIdx.y * 32;
    int tx = threadIdx.x & 31, ty = threadIdx.x >> 5;
    #pragma unroll
    for (int p = 0; p < 4; p++)
        t[ty + p * 8][tx] = src[(size_t)(t0 + ty + p * 8) * DHH + d0 + tx];
    __syncthreads();
    #pragma unroll
    for (int p = 0; p < 4; p++)
        dst[(size_t)(d0 + ty + p * 8) * TT + t0 + tx] = t[tx][ty + p * 8];
}

// ================= 64x64 core, BK=64, 4 waves, 2-PHASE double-buffered =================
// A: [M][lda] bf16 (uses K cols), B: [N][ldb] bf16. LDS halves of 4096 shorts each.
// Stage t+1 issued BEFORE compute of t; single __syncthreads per K-step drains it
// with the staging latency hidden under the MFMA phase.
__device__ __forceinline__ void gemm_loop64(const short* __restrict__ A,
                                            const short* __restrict__ B,
                                            int K, int lda, int ldb,
                                            short* As, short* Bs,
                                            f32x4 acc[2][2], int m0, int n0, int tid) {
    int wave = tid >> 6, lane = tid & 63;
    int wr = wave >> 1, wc = wave & 1;
    int lrow = lane & 15, lk = lane >> 4;
    int sr = tid >> 3, ss = tid & 7;
    int sswz = (ss ^ (sr & 7)) * 8;
    const short* Ag0 = A + (size_t)(m0 + sr) * lda + sswz;
    const short* Ag1 = A + (size_t)(m0 + sr + 32) * lda + sswz;
    const short* Bg0 = B + (size_t)(n0 + sr) * ldb + sswz;
    const short* Bg1 = B + (size_t)(n0 + sr + 32) * ldb + sswz;
    short* lA0 = As + wave * 512;
    short* lA1 = As + 2048 + wave * 512;
    short* lB0 = Bs + wave * 512;
    short* lB1 = Bs + 2048 + wave * 512;
    int nt = K >> 6;
    // prologue: stage tile 0 into half 0
    gload16(Ag0, lA0); gload16(Ag1, lA1);
    gload16(Bg0, lB0); gload16(Bg1, lB1);
    __syncthreads();
    for (int t = 0; t < nt; ++t) {
        int h = (t & 1) * 4096;
        if (t + 1 < nt) {
            int k0 = (t + 1) << 6;
            int hn = 4096 - h;
            gload16(Ag0 + k0, lA0 + hn); gload16(Ag1 + k0, lA1 + hn);
            gload16(Bg0 + k0, lB0 + hn); gload16(Bg1 + k0, lB1 + hn);
        }
        const uint4* Asc = (const uint4*)(As + h);
        const uint4* Bsc = (const uint4*)(Bs + h);
        #pragma unroll
        for (int kk = 0; kk < 2; kk++) {
            int slot = kk * 4 + lk;
            short8 a[2], b[2];
            #pragma unroll
            for (int i = 0; i < 2; i++) {
                int row = wr * 32 + i * 16 + lrow;
                uint4 v = Asc[row * 8 + (slot ^ (row & 7))];
                a[i] = *(short8*)&v;
            }
            #pragma unroll
            for (int j = 0; j < 2; j++) {
                int row = wc * 32 + j * 16 + lrow;
                uint4 v = Bsc[row * 8 + (slot ^ (row & 7))];
                b[j] = *(short8*)&v;
            }
            #pragma unroll
            for (int i = 0; i < 2; i++)
                #pragma unroll
                for (int j = 0; j < 2; j++)
                    acc[i][j] = __builtin_amdgcn_mfma_f32_16x16x32_bf16(a[i], b[j], acc[i][j], 0, 0, 0);
        }
        __syncthreads();
    }
}

// ================= 64x128 wide core, BK=64, 4 waves, 2-PHASE double-buffered =================
__device__ __forceinline__ void gemm_loop_w(const short* __restrict__ A,
                                            const short* __restrict__ B,
                                            int K, short* As, short* Bs,
                                            f32x4 acc[2][4], int m0, int n0, int tid) {
    int wave = tid >> 6, lane = tid & 63;
    int wr = wave >> 1, wc = wave & 1;
    int lrow = lane & 15, lk = lane >> 4;
    int sr = tid >> 3, ss = tid & 7;
    int sswz = (ss ^ (sr & 7)) * 8;
    const short* Ag0 = A + (size_t)(m0 + sr) * K + sswz;
    const short* Ag1 = A + (size_t)(m0 + sr + 32) * K + sswz;
    const short* Bg0 = B + (size_t)(n0 + sr) * K + sswz;
    const short* Bg1 = B + (size_t)(n0 + sr + 32) * K + sswz;
    const short* Bg2 = B + (size_t)(n0 + sr + 64) * K + sswz;
    const short* Bg3 = B + (size_t)(n0 + sr + 96) * K + sswz;
    short* lA0 = As + wave * 512;
    short* lA1 = As + 2048 + wave * 512;
    short* lB0 = Bs + wave * 512;
    short* lB1 = Bs + 2048 + wave * 512;
    short* lB2 = Bs + 4096 + wave * 512;
    short* lB3 = Bs + 6144 + wave * 512;
    int nt = K >> 6;
    gload16(Ag0, lA0); gload16(Ag1, lA1);
    gload16(Bg0, lB0); gload16(Bg1, lB1);
    gload16(Bg2, lB2); gload16(Bg3, lB3);
    __syncthreads();
    for (int t = 0; t < nt; ++t) {
        int hA = (t & 1) * 4096;
        int hB = (t & 1) * 8192;
        if (t + 1 < nt) {
            int k0 = (t + 1) << 6;
            int hnA = 4096 - hA, hnB = 8192 - hB;
            gload16(Ag0 + k0, lA0 + hnA); gload16(Ag1 + k0, lA1 + hnA);
            gload16(Bg0 + k0, lB0 + hnB); gload16(Bg1 + k0, lB1 + hnB);
            gload16(Bg2 + k0, lB2 + hnB); gload16(Bg3 + k0, lB3 + hnB);
        }
        const uint4* Asc = (const uint4*)(As + hA);
        const uint4* Bsc = (const uint4*)(Bs + hB);
        #pragma unroll
        for (int kk = 0; kk < 2; kk++) {
            int slot = kk * 4 + lk;
            short8 a[2], b[4];
            #pragma unroll
            for (int i = 0; i < 2; i++) {
                int row = wr * 32 + i * 16 + lrow;
                uint4 v = Asc[row * 8 + (slot ^ (row & 7))];
                a[i] = *(short8*)&v;
            }
            #pragma unroll
            for (int j = 0; j < 4; j++) {
                int row = wc * 64 + j * 16 + lrow;
                uint4 v = Bsc[row * 8 + (slot ^ (row & 7))];
                b[j] = *(short8*)&v;
            }
            #pragma unroll
            for (int i = 0; i < 2; i++)
                #pragma unroll
                for (int j = 0; j < 4; j++)
                    acc[i][j] = __builtin_amdgcn_mfma_f32_16x16x32_bf16(a[i], b[j], acc[i][j], 0, 0, 0);
        }
        __syncthreads();
    }
}

// ---------------- W_O GEMM (64x64): C = res + A@W^T + bias ----------------
__global__ __launch_bounds__(256) void gemm64_res_mfma(const short* __restrict__ A,
                                                       const short* __restrict__ Bw,
                                                       const float* __restrict__ bias,
                                                       const float* __restrict__ res,
                                                       float* __restrict__ C,
                                                       int N, int K) {
    __shared__ short As[8192];
    __shared__ short Bs[8192];
    int tid = threadIdx.x;
    int m0 = blockIdx.y * 64, n0 = blockIdx.x * 64;
    f32x4 acc[2][2] = {};
    gemm_loop64(A, Bw, K, K, K, As, Bs, acc, m0, n0, tid);
    int wave = tid >> 6, lane = tid & 63;
    int wr = wave >> 1, wc = wave & 1;
    int lrow = lane & 15, lk = lane >> 4;
    #pragma unroll
    for (int i = 0; i < 2; i++) {
        #pragma unroll
        for (int j = 0; j < 2; j++) {
            int col = n0 + wc * 32 + j * 16 + lrow;
            float bv = bias[col];
            #pragma unroll
            for (int r = 0; r < 4; r++) {
                int row = m0 + wr * 32 + i * 16 + lk * 4 + r;
                C[(size_t)row * N + col] = acc[i][j][r] + bv + res[(size_t)row * N + col];
            }
        }
    }
}

// ---------------- QKV GEMM (wide): bf16 out, head-major split ----------------
__global__ __launch_bounds__(256) void qkv_mfma(const short* __restrict__ A,
                                                const short* __restrict__ Bw,
                                                const float* __restrict__ bias,
                                                short* __restrict__ Qb,
                                                short* __restrict__ Kb,
                                                short* __restrict__ Vb) {
    __shared__ short As[8192];
    __shared__ short Bs[16384];
    int tid = threadIdx.x;
    int m0 = blockIdx.y * 64, n0 = blockIdx.x * 128;
    f32x4 acc[2][4] = {};
    gemm_loop_w(A, Bw, DD, As, Bs, acc, m0, n0, tid);
    int wave = tid >> 6, lane = tid & 63;
    int wr = wave >> 1, wc = wave & 1;
    int lrow = lane & 15, lk = lane >> 4;
    #pragma unroll
    for (int i = 0; i < 2; i++) {
        #pragma unroll
        for (int j = 0; j < 4; j++) {
            int col = n0 + wc * 64 + j * 16 + lrow;    // 0..3071
            int part = col >> 10;
            int rem = col & 1023;
            int h = rem >> 6, d = rem & 63;
            short* dst = (part == 0) ? Qb : ((part == 1) ? Kb : Vb);
            float bv = bias[col];
            #pragma unroll
            for (int r = 0; r < 4; r++) {
                int row = m0 + wr * 32 + i * 16 + lk * 4 + r;   // token
                int b = row >> 9, t = row & (TT - 1);
                dst[(((size_t)(b * HH + h)) * TT + t) * DHH + d] = f2b(acc[i][j][r] + bv);
            }
        }
    }
}

// ---------------- scores = Q @ K^T per (b,h), f32 out (wide) ----------------
__global__ __launch_bounds__(256) void scores_mfma(const short* __restrict__ Qb,
                                                   const short* __restrict__ Kb,
                                                   float* __restrict__ S) {
    __shared__ short As[8192];
    __shared__ short Bs[16384];
    int tid = threadIdx.x;
    int bh = blockIdx.z;
    const short* A = Qb + (size_t)bh * TT * DHH;
    const short* B = Kb + (size_t)bh * TT * DHH;
    float* Sp = S + (size_t)bh * TT * TT;
    int m0 = blockIdx.y * 64, n0 = blockIdx.x * 128;
    f32x4 acc[2][4] = {};
    gemm_loop_w(A, B, DHH, As, Bs, acc, m0, n0, tid);
    int wave = tid >> 6, lane = tid & 63;
    int wr = wave >> 1, wc = wave & 1;
    int lrow = lane & 15, lk = lane >> 4;
    #pragma unroll
    for (int i = 0; i < 2; i++)
        #pragma unroll
        for (int j = 0; j < 4; j++) {
            int col = n0 + wc * 64 + j * 16 + lrow;
            #pragma unroll
            for (int r = 0; r < 4; r++) {
                int row = m0 + wr * 32 + i * 16 + lk * 4 + r;
                Sp[(size_t)row * TT + col] = acc[i][j][r];
            }
        }
}

// ---------------- softmax rows: P = softmax(S/8 + rel_bias), bf16 out ----------------
__global__ __launch_bounds__(256) void softmax_kernel(const float* __restrict__ S,
                                                      const float* __restrict__ rel_bias,
                                                      short* __restrict__ P) {
    int row = blockIdx.x * 4 + (threadIdx.x >> 6);   // (b*H+h)*T + t
    int lane = threadIdx.x & 63;
    int t = row & (TT - 1), h = (row >> 9) & (HH - 1);
    const float* Sr = S + (size_t)row * TT;
    const float* br = rel_bias + h * (2 * TT - 1) + (TT - 1) - t;
    float v[8];
    float mx = -1e30f;
    #pragma unroll
    for (int i = 0; i < 8; i++) {
        int s = lane + i * 64;
        v[i] = Sr[s] * 0.125f + br[s];
        mx = fmaxf(mx, v[i]);
    }
    #pragma unroll
    for (int o = 32; o; o >>= 1) mx = fmaxf(mx, __shfl_xor(mx, o));
    float sum = 0.f;
    #pragma unroll
    for (int i = 0; i < 8; i++) { v[i] = expf(v[i] - mx); sum += v[i]; }
    #pragma unroll
    for (int o = 32; o; o >>= 1) sum += __shfl_xor(sum, o);
    float inv = 1.f / sum;
    #pragma unroll
    for (int i = 0; i < 8; i++)
        P[(size_t)row * TT + lane + i * 64] = f2b(v[i] * inv);
}

// ---------------- ctx = P @ V^T per (b,h), bf16 out into [t][h*64+d] ----------------
__global__ __launch_bounds__(256) void pv_mfma(const short* __restrict__ P,
                                               const short* __restrict__ VTb,
                                               short* __restrict__ ctxb) {
    __shared__ short As[8192];
    __shared__ short Bs[8192];
    int tid = threadIdx.x;
    int bh = blockIdx.z;
    int h = bh & (HH - 1), b = bh >> 4;
    const short* A = P + (size_t)bh * TT * TT;
    const short* B = VTb + (size_t)bh * DHH * TT;
    int m0 = blockIdx.y * 64;
    f32x4 acc[2][2] = {};
    gemm_loop64(A, B, TT, TT, TT, As, Bs, acc, m0, 0, tid);
    int wave = tid >> 6, lane = tid & 63;
    int wr = wave >> 1, wc = wave & 1;
    int lrow = lane & 15, lk = lane >> 4;
    #pragma unroll
    for (int i = 0; i < 2; i++)
        #pragma unroll
        for (int j = 0; j < 2; j++) {
            int d = wc * 32 + j * 16 + lrow;
            #pragma unroll
            for (int r = 0; r < 4; r++) {
                int row = m0 + wr * 32 + i * 16 + lk * 4 + r;   // t
                ctxb[((size_t)(b * TT + row)) * DD + h * DHH + d] = f2b(acc[i][j][r]);
            }
        }
}

// ---------------- MoE GEMM1 (wide): hid = gelu(Ag @ w1t[e]^T + b1[e]) (bf16 out) ----------------
__global__ __launch_bounds__(256) void moe_gemm1_mfma(const short* __restrict__ Ag,
                                                      const short* __restrict__ W1t,
                                                      const float* __restrict__ b1,
                                                      const int* __restrict__ counts,
                                                      const int* __restrict__ offs,
                                                      short* __restrict__ hid) {
    int e = blockIdx.y >> 5, tile = blockIdx.y & 31;
    int cnt = counts[e];
    int pcnt = (cnt + 63) & ~63;
    int row0 = tile * 64;
    if (row0 >= pcnt) return;
    int base = offs[e];
    const short* A  = Ag + (size_t)base * DD;
    const short* Bw = W1t + (size_t)e * FF * DD;   // [F][D]
    __shared__ short As[8192];
    __shared__ short Bs[16384];
    int tid = threadIdx.x;
    int n0 = blockIdx.x * 128;
    f32x4 acc[2][4] = {};
    gemm_loop_w(A, Bw, DD, As, Bs, acc, row0, n0, tid);
    int wave = tid >> 6, lane = tid & 63;
    int wr = wave >> 1, wc = wave & 1;
    int lrow = lane & 15, lk = lane >> 4;
    #pragma unroll
    for (int i = 0; i < 2; i++) {
        #pragma unroll
        for (int j = 0; j < 4; j++) {
            int col = n0 + wc * 64 + j * 16 + lrow;
            float bv = b1[e * FF + col];
            #pragma unroll
            for (int r = 0; r < 4; r++) {
                int row = row0 + wr * 32 + i * 16 + lk * 4 + r;
                float v = acc[i][j][r] + bv;
                float u = 0.7978845608028654f * (v + 0.044715f * v * v * v);
                float g = 0.5f * v * (1.f + tanhf(u));
                hid[(size_t)(base + row) * FF + col] = f2b(g);
            }
        }
    }
}

// ---------------- MoE GEMM2 (64x64, split-K): pair_part[s] = gate*(hid @ w2t[e]^T [+ b2]) ----------------
__global__ __launch_bounds__(256) void moe_gemm2_mfma(const short* __restrict__ hid,
                                                      const short* __restrict__ W2t,
                                                      const float* __restrict__ b2,
                                                      const float* __restrict__ pair_gate,
                                                      const int* __restrict__ counts,
                                                      const int* __restrict__ offs,
                                                      short* __restrict__ pair_part) {
    int s = blockIdx.z;                       // 0..SPL-1
    int e = blockIdx.y >> 5, tile = blockIdx.y & 31;
    int cnt = counts[e];
    int pcnt = (cnt + 63) & ~63;
    int row0 = tile * 64;
    if (row0 >= pcnt) return;
    int base = offs[e];
    const int KS = FF / SPL;
    const short* A  = hid + (size_t)base * FF + s * KS;
    const short* Bw = W2t + (size_t)e * DD * FF + s * KS;   // [D][F]
    __shared__ short As[8192];
    __shared__ short Bs[8192];
    int tid = threadIdx.x;
    int n0 = blockIdx.x * 64;
    f32x4 acc[2][2] = {};
    gemm_loop64(A, Bw, KS, FF, FF, As, Bs, acc, row0, n0, tid);
    int wave = tid >> 6, lane = tid & 63;
    int wr = wave >> 1, wc = wave & 1;
    int lrow = lane & 15, lk = lane >> 4;
    #pragma unroll
    for (int i = 0; i < 2; i++) {
        #pragma unroll
        for (int j = 0; j < 2; j++) {
            int col = n0 + wc * 32 + j * 16 + lrow;
            float bv = (s == 0) ? b2[e * DD + col] : 0.f;
            #pragma unroll
            for (int r = 0; r < 4; r++) {
                int row = row0 + wr * 32 + i * 16 + lk * 4 + r;
                float g = pair_gate[base + row];
                pair_part[((size_t)s * CAP + base + row) * DD + col] = f2b(g * (acc[i][j][r] + bv));
            }
        }
    }
}

// ---------------- text projection ----------------
__global__ __launch_bounds__(256) void txt_kernel(const float* __restrict__ ts,
                                                  const float* __restrict__ w,
                                                  const float* __restrict__ bias,
                                                  float* __restrict__ out) {
    int gid = blockIdx.x * 256 + threadIdx.x;   // 0..B*D-1
    int b = gid >> 10;
    int n = gid & (DD - 1);
    float acc = 0.f;
    for (int d = 0; d < DD; d++) acc += ts[b * DD + d] * w[(size_t)d * DD + n];
    out[gid] = acc + bias[n];
}

// ---------------- router ----------------
__global__ __launch_bounds__(256) void router_kernel(const float* __restrict__ h2,
                                                     const float* __restrict__ txt,
                                                     const float* __restrict__ w_r,
                                                     const float* __restrict__ b_r,
                                                     float* __restrict__ probs,
                                                     float* __restrict__ gates,
                                                     int* __restrict__ counts) {
    int row = blockIdx.x;       // token
    int b = row >> 9;
    int tid = threadIdx.x;
    float acc[EE] = {};
    for (int d = tid; d < DD; d += 256) {
        float r = h2[(size_t)row * DD + d] + txt[b * DD + d];
        #pragma unroll
        for (int e = 0; e < EE; e++) acc[e] += r * w_r[d * EE + e];
    }
    #pragma unroll
    for (int e = 0; e < EE; e++)
        #pragma unroll
        for (int o = 32; o; o >>= 1) acc[e] += __shfl_down(acc[e], o);
    __shared__ float lds[4][EE];
    int lane = tid & 63, w = tid >> 6;
    if (lane == 0)
        for (int e = 0; e < EE; e++) lds[w][e] = acc[e];
    __syncthreads();
    if (tid == 0) {
        float lg[EE], p[EE];
        float mx = -1e30f;
        for (int e = 0; e < EE; e++) {
            lg[e] = lds[0][e] + lds[1][e] + lds[2][e] + lds[3][e] + b_r[e];
            mx = fmaxf(mx, lg[e]);
        }
        float sum = 0.f;
        for (int e = 0; e < EE; e++) { p[e] = expf(lg[e] - mx); sum += p[e]; }
        float invs = 1.f / sum;
        for (int e = 0; e < EE; e++) { p[e] *= invs; probs[row * EE + e] = p[e]; }
        int i1 = 0;
        for (int e = 1; e < EE; e++) if (p[e] > p[i1]) i1 = e;
        int i2 = (i1 == 0) ? 1 : 0;
        for (int e = 0; e < EE; e++) if (e != i1 && p[e] > p[i2]) i2 = e;
        float gs = p[i1] + p[i2];
        for (int e = 0; e < EE; e++) gates[row * EE + e] = 0.f;
        gates[row * EE + i1] = p[i1] / gs;
        gates[row * EE + i2] = p[i2] / gs;
        atomicAdd(&counts[i1], 1);
        atomicAdd(&counts[i2], 1);
    }
}

// ---------------- expert offsets (64-aligned segments) ----------------
__global__ void offs_kernel(const int* __restrict__ counts, int* __restrict__ offs) {
    if (threadIdx.x == 0) {
        int acc = 0;
        for (int e = 0; e < EE; e++) { offs[e] = acc; acc += (counts[e] + 63) & ~63; }
    }
}

// ---------------- scatter tokens into per-expert lists ----------------
__global__ __launch_bounds__(256) void scatter_kernel(const float* __restrict__ gates,
                                                      const int* __restrict__ offs,
                                                      int* __restrict__ fill,
                                                      int* __restrict__ tok_pos,
                                                      float* __restrict__ pair_gate) {
    int t = blockIdx.x * 256 + threadIdx.x;   // token
    if (t >= NTOK) return;
    int slot = 0;
    for (int e = 0; e < EE; e++) {
        float g = gates[t * EE + e];
        if (g > 0.f) {
            int pos = offs[e] + atomicAdd(&fill[e], 1);
            tok_pos[t * 2 + slot] = pos;
            pair_gate[pos] = g;
            slot++;
        }
    }
}

// ---------------- gather tokens (h2 f32 -> bf16 rows of Ag) ----------------
__global__ __launch_bounds__(256) void gather_tokens(const float* __restrict__ h2,
                                                     const int* __restrict__ tok_pos,
                                                     short* __restrict__ Ag) {
    int i = blockIdx.x;          // 0..2047  (t = i>>1)
    int pos = tok_pos[i];
    int t = i >> 1;
    int d = threadIdx.x * 4;
    #pragma unroll
    for (int k = 0; k < 4; k++)
        Ag[(size_t)pos * DD + d + k] = f2b(h2[(size_t)t * DD + d + k]);
}

// ---------------- diag = mean(probs) ----------------
__global__ __launch_bounds__(256) void diag_kernel(const float* __restrict__ probs,
                                                   float* __restrict__ out) {
    int e = blockIdx.x;
    int tid = threadIdx.x;
    float s = 0.f;
    for (int t = tid; t < NTOK; t += 256) s += probs[t * EE + e];
    #pragma unroll
    for (int o = 32; o; o >>= 1) s += __shfl_down(s, o);
    __shared__ float red[4];
    if ((tid & 63) == 0) red[tid >> 6] = s;
    __syncthreads();
    if (tid == 0) out[e] = (red[0] + red[1] + red[2] + red[3]) * (1.f / NTOK);
}

// ---------------- final: out += sum over 2 positions x SPL splits ----------------
__global__ __launch_bounds__(256) void finaladd_kernel(float* __restrict__ out,
                                                       const short* __restrict__ pair_part,
                                                       const int* __restrict__ tok_pos) {
    int t = blockIdx.x;
    int d = threadIdx.x * 4;
    float4 a = *(const float4*)&out[(size_t)t * DD + d];
    #pragma unroll
    for (int sl = 0; sl < 2; sl++) {
        int pos = tok_pos[2 * t + sl];
        #pragma unroll
        for (int s = 0; s < SPL; s++) {
            short4 v = *(const short4*)&pair_part[((size_t)s * CAP + pos) * DD + d];
            a.x += b2f(v.x); a.y += b2f(v.y); a.z += b2f(v.z); a.w += b2f(v.w);
        }
    }
    *(float4*)&out[(size_t)t * DD + d] = a;
}

extern "C" void kernel_launch(void* const* d_in, const int* in_sizes, int n_in,
                              void* d_out, int out_size, void* d_ws, size_t ws_size,
                              hipStream_t stream) {
    const float* x          = (const float*)d_in[0];
    const float* text_state = (const float*)d_in[1];
    const float* ln1_s      = (const float*)d_in[2];
    const float* ln1_b      = (const float*)d_in[3];
    const float* w_qkv      = (const float*)d_in[4];
    const float* b_qkv      = (const float*)d_in[5];
    const float* w_o        = (const float*)d_in[6];
    const float* b_o        = (const float*)d_in[7];
    const float* rel_bias   = (const float*)d_in[8];
    const float* ln2_s      = (const float*)d_in[9];
    const float* ln2_b      = (const float*)d_in[10];
    const float* w_txt      = (const float*)d_in[11];
    const float* b_txt      = (const float*)d_in[12];
    const float* w_r        = (const float*)d_in[13];
    const float* b_r        = (const float*)d_in[14];
    const float* w1         = (const float*)d_in[15];
    const float* b1         = (const float*)d_in[16];
    const float* w2         = (const float*)d_in[17];
    const float* b2         = (const float*)d_in[18];

    float* out = (float*)d_out;   // [NTOK*D] then [E] diag

    // ---- workspace layout ----
    char* p = (char*)d_ws;
    auto alloc = [&](size_t bytes) { char* r = p; p += (bytes + 255) & ~(size_t)255; return r; };
    short* h1b      = (short*)alloc((size_t)NTOK * DD * 2);
    short* Qb       = (short*)alloc((size_t)NTOK * DD * 2);
    short* Kb       = (short*)alloc((size_t)NTOK * DD * 2);
    short* Vb       = (short*)alloc((size_t)NTOK * DD * 2);
    short* VTb      = (short*)alloc((size_t)NTOK * DD * 2);
    // region1: S (f32 33.5MB) -> later Ag(5.2MB)+hid(21MB)
    char*  region1  = alloc((size_t)BB * HH * TT * TT * 4);
    // region2: P (bf16 16.8MB) -> later pair_part (SPL x CAP x DD bf16 = 10.5MB)
    char*  region2  = alloc((size_t)BB * HH * TT * TT * 2);
    short* ctxb     = (short*)alloc((size_t)NTOK * DD * 2);
    float* h2       = (float*)alloc((size_t)NTOK * DD * 4);
    float* txt      = (float*)alloc((size_t)BB * DD * 4);
    float* probs    = (float*)alloc((size_t)NTOK * EE * 4);
    float* gates    = (float*)alloc((size_t)NTOK * EE * 4);
    float* pair_gate= (float*)alloc((size_t)CAP * 4);
    int*   counts   = (int*)alloc(8 * 4);
    int*   fill     = (int*)alloc(8 * 4);
    int*   offs     = (int*)alloc(8 * 4);
    int*   tok_pos  = (int*)alloc((size_t)NTOK * 2 * 4);
    short* wqkvT    = (short*)alloc((size_t)3 * DD * DD * 2);        // [3D][D]
    short* woT      = (short*)alloc((size_t)DD * DD * 2);            // [D][D]
    short* w1T      = (short*)alloc((size_t)EE * FF * DD * 2);       // [E][F][D]
    short* w2T      = (short*)alloc((size_t)EE * DD * FF * 2);       // [E][D][F]

    float* S         = (float*)region1;
    short* P         = (short*)region2;
    short* Ag        = (short*)region1;                              // after attn
    short* hid       = (short*)(region1 + (((size_t)CAP * DD * 2 + 255) & ~(size_t)255));
    short* pair_part = (short*)region2;                              // after attn

    // ---- weight prep ----
    transpose_cast<<<dim3(3 * DD / 64, DD / 64, 1), 256, 0, stream>>>(w_qkv, wqkvT, DD, 3 * DD);
    transpose_cast<<<dim3(DD / 64, DD / 64, 1), 256, 0, stream>>>(w_o, woT, DD, DD);
    transpose_cast<<<dim3(FF / 64, DD / 64, EE), 256, 0, stream>>>(w1, w1T, DD, FF);
    transpose_cast<<<dim3(DD / 64, FF / 64, EE), 256, 0, stream>>>(w2, w2T, FF, DD);

    // ---- 1. LN1 (bf16 out) ----
    ln_kernel<1><<<NTOK, 256, 0, stream>>>(x, ln1_s, ln1_b, h1b);
    // ---- 2. QKV GEMM -> bf16 head-major Q/K/V ----
    qkv_mfma<<<dim3(3 * DD / 128, NTOK / 64), 256, 0, stream>>>(h1b, wqkvT, b_qkv, Qb, Kb, Vb);
    // ---- 3. V transpose per (b,h) ----
    v_transpose<<<dim3(TT / 32, DHH / 32, BB * HH), 256, 0, stream>>>(Vb, VTb);
    // ---- 4. scores ----
    scores_mfma<<<dim3(TT / 128, TT / 64, BB * HH), 256, 0, stream>>>(Qb, Kb, S);
    // ---- 5. softmax (scale + rel bias folded) ----
    softmax_kernel<<<BB * HH * TT / 4, 256, 0, stream>>>(S, rel_bias, P);
    // ---- 6. ctx = P @ V^T ----
    pv_mfma<<<dim3(1, TT / 64, BB * HH), 256, 0, stream>>>(P, VTb, ctxb);
    // ---- 7. x1 = x + ctx @ w_o + b_o -> out ----
    gemm64_res_mfma<<<dim3(DD / 64, NTOK / 64), 256, 0, stream>>>(ctxb, woT, b_o, x, out, DD, DD);
    // ---- 8. LN2 (f32 out) ----
    ln_kernel<0><<<NTOK, 256, 0, stream>>>(out, ln2_s, ln2_b, h2);
    // ---- 9. text projection ----
    txt_kernel<<<(BB * DD) / 256, 256, 0, stream>>>(text_state, w_txt, b_txt, txt);
    // ---- 10. zero scratch ----
    hipMemsetAsync(counts, 0, 8 * 4, stream);
    hipMemsetAsync(fill, 0, 8 * 4, stream);
    hipMemsetAsync(Ag, 0, (size_t)CAP * DD * 2, stream);
    // ---- 11. router ----
    router_kernel<<<NTOK, 256, 0, stream>>>(h2, txt, w_r, b_r, probs, gates, counts);
    // ---- 12. aligned offsets ----
    offs_kernel<<<1, 64, 0, stream>>>(counts, offs);
    // ---- 13. scatter ----
    scatter_kernel<<<NTOK / 256, 256, 0, stream>>>(gates, offs, fill, tok_pos, pair_gate);
    // ---- 14. gather rows into Ag (bf16) ----
    gather_tokens<<<NTOK * 2, 256, 0, stream>>>(h2, tok_pos, Ag);
    // ---- 15. diag ----
    diag_kernel<<<EE, 256, 0, stream>>>(probs, out + (size_t)NTOK * DD);
    // ---- 16. MoE GEMM1 (wide) ----
    moe_gemm1_mfma<<<dim3(FF / 128, EE * 32), 256, 0, stream>>>(Ag, w1T, b1, counts, offs, hid);
    // ---- 17. MoE GEMM2 (64x64, split-K) ----
    moe_gemm2_mfma<<<dim3(DD / 64, EE * 32, SPL), 256, 0, stream>>>(hid, w2T, b2, pair_gate, counts, offs, pair_part);
    // ---- 18. final add (sums splits) ----
    finaladd_kernel<<<NTOK, 256, 0, stream>>>(out, pair_part, tok_pos);
}

// Round 6
// 335.406 us; speedup vs baseline: 1.3030x; 1.2169x over previous
//
#include <hip/hip_runtime.h>
#include <hip/hip_bf16.h>
#include <math.h>

// Problem constants
#define BB 2
#define TT 512
#define DD 1024
#define HH 16
#define DHH 64
#define EE 8
#define FF 4096
#define NTOK 1024
#define CAP 3072   // >= 2048 + 8*127 rounded up to 128
#define SPL 2      // split-K factor for moe_gemm2

typedef __attribute__((ext_vector_type(4))) float f32x4;
typedef __attribute__((ext_vector_type(8))) short short8;

__device__ __forceinline__ short f2b(float f) {
    __hip_bfloat16 h = __float2bfloat16(f);
    return *reinterpret_cast<short*>(&h);
}
__device__ __forceinline__ float b2f(short s) {
    __hip_bfloat16 h = *reinterpret_cast<__hip_bfloat16*>(&s);
    return __bfloat162float(h);
}

// async global->LDS, 16B per lane. LDS dest = wave-uniform base + lane*16.
__device__ __forceinline__ void gload16(const short* g, short* l) {
    __builtin_amdgcn_global_load_lds((const __attribute__((address_space(1))) unsigned int*)g,
                                     (__attribute__((address_space(3))) unsigned int*)l,
                                     16, 0, 0);
}

// ---------------- LayerNorm (templated output dtype) ----------------
template <int BF>
__global__ __launch_bounds__(256) void ln_kernel(const float* __restrict__ x,
                                                 const float* __restrict__ s,
                                                 const float* __restrict__ b,
                                                 void* __restrict__ outp) {
    int row = blockIdx.x;
    int tid = threadIdx.x;
    const float* xr = x + (size_t)row * DD;
    float sm = 0.f, sq = 0.f;
    for (int i = tid; i < DD; i += 256) {
        float v = xr[i];
        sm += v; sq += v * v;
    }
    #pragma unroll
    for (int o = 32; o; o >>= 1) {
        sm += __shfl_down(sm, o);
        sq += __shfl_down(sq, o);
    }
    __shared__ float r1[4], r2[4];
    if ((tid & 63) == 0) { r1[tid >> 6] = sm; r2[tid >> 6] = sq; }
    __syncthreads();
    float tot  = r1[0] + r1[1] + r1[2] + r1[3];
    float totq = r2[0] + r2[1] + r2[2] + r2[3];
    float mu  = tot * (1.f / DD);
    float var = totq * (1.f / DD) - mu * mu;
    float inv = rsqrtf(var + 1e-5f);
    for (int i = tid; i < DD; i += 256) {
        float v = (xr[i] - mu) * inv * s[i] + b[i];
        if (BF) ((short*)outp)[(size_t)row * DD + i] = f2b(v);
        else    ((float*)outp)[(size_t)row * DD + i] = v;
    }
}

// ---------------- Transpose + cast f32 [K][N] -> bf16 [N][K], 64x64 tiles ----------------
__global__ __launch_bounds__(256) void transpose_cast(const float* __restrict__ src,
                                                      short* __restrict__ dst,
                                                      int K, int N) {
    __shared__ float t[64][65];
    src += (size_t)blockIdx.z * K * N;
    dst += (size_t)blockIdx.z * K * N;
    int k0 = blockIdx.y * 64, n0 = blockIdx.x * 64;
    int rr = threadIdx.x >> 4;           // 0..15
    int cc = (threadIdx.x & 15) * 4;     // 0..60
    #pragma unroll
    for (int p = 0; p < 4; p++) {
        float4 v = *(const float4*)&src[(size_t)(k0 + rr + p * 16) * N + n0 + cc];
        t[rr + p * 16][cc]     = v.x;
        t[rr + p * 16][cc + 1] = v.y;
        t[rr + p * 16][cc + 2] = v.z;
        t[rr + p * 16][cc + 3] = v.w;
    }
    __syncthreads();
    #pragma unroll
    for (int p = 0; p < 4; p++) {
        int n = rr + p * 16;
        short4 o;
        o.x = f2b(t[cc][n]); o.y = f2b(t[cc + 1][n]);
        o.z = f2b(t[cc + 2][n]); o.w = f2b(t[cc + 3][n]);
        *(short4*)&dst[(size_t)(n0 + n) * K + k0 + cc] = o;
    }
}

// ---------------- bf16 -> bf16 transpose V[t][d] -> VT[d][t] per (b,h) ----------------
__global__ __launch_bounds__(256) void v_transpose(const short* __restrict__ Vb,
                                                   short* __restrict__ VTb) {
    __shared__ short t[32][33];
    int bh = blockIdx.z;
    const short* src = Vb + (size_t)bh * TT * DHH;
    short* dst = VTb + (size_t)bh * DHH * TT;
    int t0 = blockIdx.x * 32, d0 = blockIdx.y * 32;
    int tx = threadIdx.x & 31, ty = threadIdx.x >> 5;
    #pragma unroll
    for (int p = 0; p < 4; p++)
        t[ty + p * 8][tx] = src[(size_t)(t0 + ty + p * 8) * DHH + d0 + tx];
    __syncthreads();
    #pragma unroll
    for (int p = 0; p < 4; p++)
        dst[(size_t)(d0 + ty + p * 8) * TT + t0 + tx] = t[tx][ty + p * 8];
}

// ================= 128x128 core, BK=64, 4 waves (m97 structure) =================
// A: [M][lda] bf16, B: [N][ldb] bf16. Wave w owns 64x64 at (wr*64, wc*64); acc[4][4].
// Single-buffered 16KB+16KB LDS; stage -> sync -> compute -> sync per K-step.
// Swizzle: LDS[r][s] holds global slot s^(r&7); stage source slot = (lane&7)^(lane>>3).
__device__ __forceinline__ void gemm_loop128(const short* __restrict__ A,
                                             const short* __restrict__ B,
                                             int K, int lda, int ldb,
                                             short* As, short* Bs,
                                             f32x4 acc[4][4], int m0, int n0, int tid) {
    int wave = tid >> 6, lane = tid & 63;
    int wr = wave >> 1, wc = wave & 1;
    int lrow = lane & 15, lk = lane >> 4;
    int srow = lane >> 3;                 // 0..7 within 8-row group
    int sslot = (lane & 7) ^ srow;        // inverse-swizzled 16B slot
    const short* Agb = A + (size_t)(m0 + srow) * lda + sslot * 8;
    const short* Bgb = B + (size_t)(n0 + srow) * ldb + sslot * 8;
    for (int k0 = 0; k0 < K; k0 += 64) {
        // ---- stage 128x64 A and B ----
        #pragma unroll
        for (int p = 0; p < 4; p++) {
            int rg = (wave * 4 + p) * 8;            // row group base 0..120
            gload16(Agb + (size_t)rg * lda + k0, As + rg * 64);
            gload16(Bgb + (size_t)rg * ldb + k0, Bs + rg * 64);
        }
        __syncthreads();
        // ---- compute ----
        #pragma unroll
        for (int kk = 0; kk < 2; kk++) {
            int q = kk * 4 + lk;
            short8 a[4], b[4];
            #pragma unroll
            for (int i = 0; i < 4; i++) {
                int r = wr * 64 + i * 16 + lrow;
                uint4 v = ((const uint4*)As)[r * 8 + (q ^ (r & 7))];
                a[i] = *(short8*)&v;
            }
            #pragma unroll
            for (int j = 0; j < 4; j++) {
                int r = wc * 64 + j * 16 + lrow;
                uint4 v = ((const uint4*)Bs)[r * 8 + (q ^ (r & 7))];
                b[j] = *(short8*)&v;
            }
            #pragma unroll
            for (int i = 0; i < 4; i++)
                #pragma unroll
                for (int j = 0; j < 4; j++)
                    acc[i][j] = __builtin_amdgcn_mfma_f32_16x16x32_bf16(a[i], b[j], acc[i][j], 0, 0, 0);
        }
        __syncthreads();
    }
}

// ================= 64x64 core, BK=64, 4 waves, 2-PHASE double-buffered =================
__device__ __forceinline__ void gemm_loop64(const short* __restrict__ A,
                                            const short* __restrict__ B,
                                            int K, int lda, int ldb,
                                            short* As, short* Bs,
                                            f32x4 acc[2][2], int m0, int n0, int tid) {
    int wave = tid >> 6, lane = tid & 63;
    int wr = wave >> 1, wc = wave & 1;
    int lrow = lane & 15, lk = lane >> 4;
    int sr = tid >> 3, ss = tid & 7;
    int sswz = (ss ^ (sr & 7)) * 8;
    const short* Ag0 = A + (size_t)(m0 + sr) * lda + sswz;
    const short* Ag1 = A + (size_t)(m0 + sr + 32) * lda + sswz;
    const short* Bg0 = B + (size_t)(n0 + sr) * ldb + sswz;
    const short* Bg1 = B + (size_t)(n0 + sr + 32) * ldb + sswz;
    short* lA0 = As + wave * 512;
    short* lA1 = As + 2048 + wave * 512;
    short* lB0 = Bs + wave * 512;
    short* lB1 = Bs + 2048 + wave * 512;
    int nt = K >> 6;
    gload16(Ag0, lA0); gload16(Ag1, lA1);
    gload16(Bg0, lB0); gload16(Bg1, lB1);
    __syncthreads();
    for (int t = 0; t < nt; ++t) {
        int h = (t & 1) * 4096;
        if (t + 1 < nt) {
            int k0 = (t + 1) << 6;
            int hn = 4096 - h;
            gload16(Ag0 + k0, lA0 + hn); gload16(Ag1 + k0, lA1 + hn);
            gload16(Bg0 + k0, lB0 + hn); gload16(Bg1 + k0, lB1 + hn);
        }
        const uint4* Asc = (const uint4*)(As + h);
        const uint4* Bsc = (const uint4*)(Bs + h);
        #pragma unroll
        for (int kk = 0; kk < 2; kk++) {
            int slot = kk * 4 + lk;
            short8 a[2], b[2];
            #pragma unroll
            for (int i = 0; i < 2; i++) {
                int row = wr * 32 + i * 16 + lrow;
                uint4 v = Asc[row * 8 + (slot ^ (row & 7))];
                a[i] = *(short8*)&v;
            }
            #pragma unroll
            for (int j = 0; j < 2; j++) {
                int row = wc * 32 + j * 16 + lrow;
                uint4 v = Bsc[row * 8 + (slot ^ (row & 7))];
                b[j] = *(short8*)&v;
            }
            #pragma unroll
            for (int i = 0; i < 2; i++)
                #pragma unroll
                for (int j = 0; j < 2; j++)
                    acc[i][j] = __builtin_amdgcn_mfma_f32_16x16x32_bf16(a[i], b[j], acc[i][j], 0, 0, 0);
        }
        __syncthreads();
    }
}

// ================= 64x128 wide core, BK=64, 4 waves, 2-PHASE double-buffered =================
__device__ __forceinline__ void gemm_loop_w(const short* __restrict__ A,
                                            const short* __restrict__ B,
                                            int K, short* As, short* Bs,
                                            f32x4 acc[2][4], int m0, int n0, int tid) {
    int wave = tid >> 6, lane = tid & 63;
    int wr = wave >> 1, wc = wave & 1;
    int lrow = lane & 15, lk = lane >> 4;
    int sr = tid >> 3, ss = tid & 7;
    int sswz = (ss ^ (sr & 7)) * 8;
    const short* Ag0 = A + (size_t)(m0 + sr) * K + sswz;
    const short* Ag1 = A + (size_t)(m0 + sr + 32) * K + sswz;
    const short* Bg0 = B + (size_t)(n0 + sr) * K + sswz;
    const short* Bg1 = B + (size_t)(n0 + sr + 32) * K + sswz;
    const short* Bg2 = B + (size_t)(n0 + sr + 64) * K + sswz;
    const short* Bg3 = B + (size_t)(n0 + sr + 96) * K + sswz;
    short* lA0 = As + wave * 512;
    short* lA1 = As + 2048 + wave * 512;
    short* lB0 = Bs + wave * 512;
    short* lB1 = Bs + 2048 + wave * 512;
    short* lB2 = Bs + 4096 + wave * 512;
    short* lB3 = Bs + 6144 + wave * 512;
    int nt = K >> 6;
    gload16(Ag0, lA0); gload16(Ag1, lA1);
    gload16(Bg0, lB0); gload16(Bg1, lB1);
    gload16(Bg2, lB2); gload16(Bg3, lB3);
    __syncthreads();
    for (int t = 0; t < nt; ++t) {
        int hA = (t & 1) * 4096;
        int hB = (t & 1) * 8192;
        if (t + 1 < nt) {
            int k0 = (t + 1) << 6;
            int hnA = 4096 - hA, hnB = 8192 - hB;
            gload16(Ag0 + k0, lA0 + hnA); gload16(Ag1 + k0, lA1 + hnA);
            gload16(Bg0 + k0, lB0 + hnB); gload16(Bg1 + k0, lB1 + hnB);
            gload16(Bg2 + k0, lB2 + hnB); gload16(Bg3 + k0, lB3 + hnB);
        }
        const uint4* Asc = (const uint4*)(As + hA);
        const uint4* Bsc = (const uint4*)(Bs + hB);
        #pragma unroll
        for (int kk = 0; kk < 2; kk++) {
            int slot = kk * 4 + lk;
            short8 a[2], b[4];
            #pragma unroll
            for (int i = 0; i < 2; i++) {
                int row = wr * 32 + i * 16 + lrow;
                uint4 v = Asc[row * 8 + (slot ^ (row & 7))];
                a[i] = *(short8*)&v;
            }
            #pragma unroll
            for (int j = 0; j < 4; j++) {
                int row = wc * 64 + j * 16 + lrow;
                uint4 v = Bsc[row * 8 + (slot ^ (row & 7))];
                b[j] = *(short8*)&v;
            }
            #pragma unroll
            for (int i = 0; i < 2; i++)
                #pragma unroll
                for (int j = 0; j < 4; j++)
                    acc[i][j] = __builtin_amdgcn_mfma_f32_16x16x32_bf16(a[i], b[j], acc[i][j], 0, 0, 0);
        }
        __syncthreads();
    }
}

// ---------------- W_O GEMM (64x64): C = res + A@W^T + bias ----------------
__global__ __launch_bounds__(256) void gemm64_res_mfma(const short* __restrict__ A,
                                                       const short* __restrict__ Bw,
                                                       const float* __restrict__ bias,
                                                       const float* __restrict__ res,
                                                       float* __restrict__ C,
                                                       int N, int K) {
    __shared__ short As[8192];
    __shared__ short Bs[8192];
    int tid = threadIdx.x;
    int m0 = blockIdx.y * 64, n0 = blockIdx.x * 64;
    f32x4 acc[2][2] = {};
    gemm_loop64(A, Bw, K, K, K, As, Bs, acc, m0, n0, tid);
    int wave = tid >> 6, lane = tid & 63;
    int wr = wave >> 1, wc = wave & 1;
    int lrow = lane & 15, lk = lane >> 4;
    #pragma unroll
    for (int i = 0; i < 2; i++) {
        #pragma unroll
        for (int j = 0; j < 2; j++) {
            int col = n0 + wc * 32 + j * 16 + lrow;
            float bv = bias[col];
            #pragma unroll
            for (int r = 0; r < 4; r++) {
                int row = m0 + wr * 32 + i * 16 + lk * 4 + r;
                C[(size_t)row * N + col] = acc[i][j][r] + bv + res[(size_t)row * N + col];
            }
        }
    }
}

// ---------------- QKV GEMM (wide): bf16 out, head-major split ----------------
__global__ __launch_bounds__(256) void qkv_mfma(const short* __restrict__ A,
                                                const short* __restrict__ Bw,
                                                const float* __restrict__ bias,
                                                short* __restrict__ Qb,
                                                short* __restrict__ Kb,
                                                short* __restrict__ Vb) {
    __shared__ short As[8192];
    __shared__ short Bs[16384];
    int tid = threadIdx.x;
    int m0 = blockIdx.y * 64, n0 = blockIdx.x * 128;
    f32x4 acc[2][4] = {};
    gemm_loop_w(A, Bw, DD, As, Bs, acc, m0, n0, tid);
    int wave = tid >> 6, lane = tid & 63;
    int wr = wave >> 1, wc = wave & 1;
    int lrow = lane & 15, lk = lane >> 4;
    #pragma unroll
    for (int i = 0; i < 2; i++) {
        #pragma unroll
        for (int j = 0; j < 4; j++) {
            int col = n0 + wc * 64 + j * 16 + lrow;    // 0..3071
            int part = col >> 10;
            int rem = col & 1023;
            int h = rem >> 6, d = rem & 63;
            short* dst = (part == 0) ? Qb : ((part == 1) ? Kb : Vb);
            float bv = bias[col];
            #pragma unroll
            for (int r = 0; r < 4; r++) {
                int row = m0 + wr * 32 + i * 16 + lk * 4 + r;   // token
                int b = row >> 9, t = row & (TT - 1);
                dst[(((size_t)(b * HH + h)) * TT + t) * DHH + d] = f2b(acc[i][j][r] + bv);
            }
        }
    }
}

// ---------------- scores = Q @ K^T per (b,h), f32 out (wide) ----------------
__global__ __launch_bounds__(256) void scores_mfma(const short* __restrict__ Qb,
                                                   const short* __restrict__ Kb,
                                                   float* __restrict__ S) {
    __shared__ short As[8192];
    __shared__ short Bs[16384];
    int tid = threadIdx.x;
    int bh = blockIdx.z;
    const short* A = Qb + (size_t)bh * TT * DHH;
    const short* B = Kb + (size_t)bh * TT * DHH;
    float* Sp = S + (size_t)bh * TT * TT;
    int m0 = blockIdx.y * 64, n0 = blockIdx.x * 128;
    f32x4 acc[2][4] = {};
    gemm_loop_w(A, B, DHH, As, Bs, acc, m0, n0, tid);
    int wave = tid >> 6, lane = tid & 63;
    int wr = wave >> 1, wc = wave & 1;
    int lrow = lane & 15, lk = lane >> 4;
    #pragma unroll
    for (int i = 0; i < 2; i++)
        #pragma unroll
        for (int j = 0; j < 4; j++) {
            int col = n0 + wc * 64 + j * 16 + lrow;
            #pragma unroll
            for (int r = 0; r < 4; r++) {
                int row = m0 + wr * 32 + i * 16 + lk * 4 + r;
                Sp[(size_t)row * TT + col] = acc[i][j][r];
            }
        }
}

// ---------------- softmax rows: P = softmax(S/8 + rel_bias), bf16 out ----------------
__global__ __launch_bounds__(256) void softmax_kernel(const float* __restrict__ S,
                                                      const float* __restrict__ rel_bias,
                                                      short* __restrict__ P) {
    int row = blockIdx.x * 4 + (threadIdx.x >> 6);   // (b*H+h)*T + t
    int lane = threadIdx.x & 63;
    int t = row & (TT - 1), h = (row >> 9) & (HH - 1);
    const float* Sr = S + (size_t)row * TT;
    const float* br = rel_bias + h * (2 * TT - 1) + (TT - 1) - t;
    float v[8];
    float mx = -1e30f;
    #pragma unroll
    for (int i = 0; i < 8; i++) {
        int s = lane + i * 64;
        v[i] = Sr[s] * 0.125f + br[s];
        mx = fmaxf(mx, v[i]);
    }
    #pragma unroll
    for (int o = 32; o; o >>= 1) mx = fmaxf(mx, __shfl_xor(mx, o));
    float sum = 0.f;
    #pragma unroll
    for (int i = 0; i < 8; i++) { v[i] = expf(v[i] - mx); sum += v[i]; }
    #pragma unroll
    for (int o = 32; o; o >>= 1) sum += __shfl_xor(sum, o);
    float inv = 1.f / sum;
    #pragma unroll
    for (int i = 0; i < 8; i++)
        P[(size_t)row * TT + lane + i * 64] = f2b(v[i] * inv);
}

// ---------------- ctx = P @ V^T per (b,h), bf16 out into [t][h*64+d] ----------------
__global__ __launch_bounds__(256) void pv_mfma(const short* __restrict__ P,
                                               const short* __restrict__ VTb,
                                               short* __restrict__ ctxb) {
    __shared__ short As[8192];
    __shared__ short Bs[8192];
    int tid = threadIdx.x;
    int bh = blockIdx.z;
    int h = bh & (HH - 1), b = bh >> 4;
    const short* A = P + (size_t)bh * TT * TT;
    const short* B = VTb + (size_t)bh * DHH * TT;
    int m0 = blockIdx.y * 64;
    f32x4 acc[2][2] = {};
    gemm_loop64(A, B, TT, TT, TT, As, Bs, acc, m0, 0, tid);
    int wave = tid >> 6, lane = tid & 63;
    int wr = wave >> 1, wc = wave & 1;
    int lrow = lane & 15, lk = lane >> 4;
    #pragma unroll
    for (int i = 0; i < 2; i++)
        #pragma unroll
        for (int j = 0; j < 2; j++) {
            int d = wc * 32 + j * 16 + lrow;
            #pragma unroll
            for (int r = 0; r < 4; r++) {
                int row = m0 + wr * 32 + i * 16 + lk * 4 + r;   // t
                ctxb[((size_t)(b * TT + row)) * DD + h * DHH + d] = f2b(acc[i][j][r]);
            }
        }
}

// ---------------- MoE GEMM1 (128x128): hid = gelu(Ag @ w1t[e]^T + b1[e]) (bf16 out) ----------------
__global__ __launch_bounds__(256) void moe_gemm1_mfma(const short* __restrict__ Ag,
                                                      const short* __restrict__ W1t,
                                                      const float* __restrict__ b1,
                                                      const int* __restrict__ counts,
                                                      const int* __restrict__ offs,
                                                      short* __restrict__ hid) {
    int e = blockIdx.y >> 4, tile = blockIdx.y & 15;
    int cnt = counts[e];
    int pcnt = (cnt + 127) & ~127;
    int row0 = tile * 128;
    if (row0 >= pcnt) return;
    int base = offs[e];
    const short* A  = Ag + (size_t)base * DD;
    const short* Bw = W1t + (size_t)e * FF * DD;   // [F][D]
    __shared__ short As[8192];
    __shared__ short Bs[8192];
    int tid = threadIdx.x;
    int n0 = blockIdx.x * 128;
    f32x4 acc[4][4] = {};
    gemm_loop128(A, Bw, DD, DD, DD, As, Bs, acc, row0, n0, tid);
    int wave = tid >> 6, lane = tid & 63;
    int wr = wave >> 1, wc = wave & 1;
    int lrow = lane & 15, lk = lane >> 4;
    #pragma unroll
    for (int i = 0; i < 4; i++) {
        #pragma unroll
        for (int j = 0; j < 4; j++) {
            int col = n0 + wc * 64 + j * 16 + lrow;
            float bv = b1[e * FF + col];
            #pragma unroll
            for (int r = 0; r < 4; r++) {
                int row = row0 + wr * 64 + i * 16 + lk * 4 + r;
                float v = acc[i][j][r] + bv;
                float u = 0.7978845608028654f * (v + 0.044715f * v * v * v);
                float g = 0.5f * v * (1.f + tanhf(u));
                hid[(size_t)(base + row) * FF + col] = f2b(g);
            }
        }
    }
}

// ---------------- MoE GEMM2 (128x128, split-K): pair_part[s] = gate*(hid @ w2t[e]^T [+ b2]) ----------------
__global__ __launch_bounds__(256) void moe_gemm2_mfma(const short* __restrict__ hid,
                                                      const short* __restrict__ W2t,
                                                      const float* __restrict__ b2,
                                                      const float* __restrict__ pair_gate,
                                                      const int* __restrict__ counts,
                                                      const int* __restrict__ offs,
                                                      short* __restrict__ pair_part) {
    int s = blockIdx.z;                       // 0..SPL-1
    int e = blockIdx.y >> 4, tile = blockIdx.y & 15;
    int cnt = counts[e];
    int pcnt = (cnt + 127) & ~127;
    int row0 = tile * 128;
    if (row0 >= pcnt) return;
    int base = offs[e];
    const int KS = FF / SPL;
    const short* A  = hid + (size_t)base * FF + s * KS;
    const short* Bw = W2t + (size_t)e * DD * FF + s * KS;   // [D][F]
    __shared__ short As[8192];
    __shared__ short Bs[8192];
    int tid = threadIdx.x;
    int n0 = blockIdx.x * 128;
    f32x4 acc[4][4] = {};
    gemm_loop128(A, Bw, KS, FF, FF, As, Bs, acc, row0, n0, tid);
    int wave = tid >> 6, lane = tid & 63;
    int wr = wave >> 1, wc = wave & 1;
    int lrow = lane & 15, lk = lane >> 4;
    #pragma unroll
    for (int i = 0; i < 4; i++) {
        #pragma unroll
        for (int j = 0; j < 4; j++) {
            int col = n0 + wc * 64 + j * 16 + lrow;
            float bv = (s == 0) ? b2[e * DD + col] : 0.f;
            #pragma unroll
            for (int r = 0; r < 4; r++) {
                int row = row0 + wr * 64 + i * 16 + lk * 4 + r;
                float g = pair_gate[base + row];
                pair_part[((size_t)s * CAP + base + row) * DD + col] = f2b(g * (acc[i][j][r] + bv));
            }
        }
    }
}

// ---------------- text projection: out[b][col] = ts[b,:] @ w[:,col] + bias ----------------
__global__ __launch_bounds__(256) void txt_kernel(const float* __restrict__ ts,
                                                  const float* __restrict__ w,
                                                  const float* __restrict__ bias,
                                                  float* __restrict__ out) {
    int b = blockIdx.y;
    int col = blockIdx.x * 32 + (threadIdx.x & 31);
    int dg = threadIdx.x >> 5;                 // 0..7
    float acc = 0.f;
    for (int d = dg * 128; d < dg * 128 + 128; d++)
        acc += ts[b * DD + d] * w[(size_t)d * DD + col];
    __shared__ float red[8][32];
    red[dg][threadIdx.x & 31] = acc;
    __syncthreads();
    if (threadIdx.x < 32) {
        float s = 0.f;
        #pragma unroll
        for (int g = 0; g < 8; g++) s += red[g][threadIdx.x];
        out[b * DD + col] = s + bias[col];
    }
}

// ---------------- router ----------------
__global__ __launch_bounds__(256) void router_kernel(const float* __restrict__ h2,
                                                     const float* __restrict__ txt,
                                                     const float* __restrict__ w_r,
                                                     const float* __restrict__ b_r,
                                                     float* __restrict__ probs,
                                                     float* __restrict__ gates,
                                                     int* __restrict__ counts) {
    int row = blockIdx.x;       // token
    int b = row >> 9;
    int tid = threadIdx.x;
    float acc[EE] = {};
    for (int d = tid; d < DD; d += 256) {
        float r = h2[(size_t)row * DD + d] + txt[b * DD + d];
        #pragma unroll
        for (int e = 0; e < EE; e++) acc[e] += r * w_r[d * EE + e];
    }
    #pragma unroll
    for (int e = 0; e < EE; e++)
        #pragma unroll
        for (int o = 32; o; o >>= 1) acc[e] += __shfl_down(acc[e], o);
    __shared__ float lds[4][EE];
    int lane = tid & 63, w = tid >> 6;
    if (lane == 0)
        for (int e = 0; e < EE; e++) lds[w][e] = acc[e];
    __syncthreads();
    if (tid == 0) {
        float lg[EE], p[EE];
        float mx = -1e30f;
        for (int e = 0; e < EE; e++) {
            lg[e] = lds[0][e] + lds[1][e] + lds[2][e] + lds[3][e] + b_r[e];
            mx = fmaxf(mx, lg[e]);
        }
        float sum = 0.f;
        for (int e = 0; e < EE; e++) { p[e] = expf(lg[e] - mx); sum += p[e]; }
        float invs = 1.f / sum;
        for (int e = 0; e < EE; e++) { p[e] *= invs; probs[row * EE + e] = p[e]; }
        int i1 = 0;
        for (int e = 1; e < EE; e++) if (p[e] > p[i1]) i1 = e;
        int i2 = (i1 == 0) ? 1 : 0;
        for (int e = 0; e < EE; e++) if (e != i1 && p[e] > p[i2]) i2 = e;
        float gs = p[i1] + p[i2];
        for (int e = 0; e < EE; e++) gates[row * EE + e] = 0.f;
        gates[row * EE + i1] = p[i1] / gs;
        gates[row * EE + i2] = p[i2] / gs;
        atomicAdd(&counts[i1], 1);
        atomicAdd(&counts[i2], 1);
    }
}

// ---------------- expert offsets (128-aligned segments) ----------------
__global__ void offs_kernel(const int* __restrict__ counts, int* __restrict__ offs) {
    if (threadIdx.x == 0) {
        int acc = 0;
        for (int e = 0; e < EE; e++) { offs[e] = acc; acc += (counts[e] + 127) & ~127; }
    }
}

// ---------------- scatter tokens into per-expert lists ----------------
__global__ __launch_bounds__(256) void scatter_kernel(const float* __restrict__ gates,
                                                      const int* __restrict__ offs,
                                                      int* __restrict__ fill,
                                                      int* __restrict__ tok_pos,
                                                      float* __restrict__ pair_gate) {
    int t = blockIdx.x * 256 + threadIdx.x;   // token
    if (t >= NTOK) return;
    int slot = 0;
    for (int e = 0; e < EE; e++) {
        float g = gates[t * EE + e];
        if (g > 0.f) {
            int pos = offs[e] + atomicAdd(&fill[e], 1);
            tok_pos[t * 2 + slot] = pos;
            pair_gate[pos] = g;
            slot++;
        }
    }
}

// ---------------- gather tokens (h2 f32 -> bf16 rows of Ag) ----------------
__global__ __launch_bounds__(256) void gather_tokens(const float* __restrict__ h2,
                                                     const int* __restrict__ tok_pos,
                                                     short* __restrict__ Ag) {
    int i = blockIdx.x;          // 0..2047  (t = i>>1)
    int pos = tok_pos[i];
    int t = i >> 1;
    int d = threadIdx.x * 4;
    #pragma unroll
    for (int k = 0; k < 4; k++)
        Ag[(size_t)pos * DD + d + k] = f2b(h2[(size_t)t * DD + d + k]);
}

// ---------------- diag = mean(probs) ----------------
__global__ __launch_bounds__(256) void diag_kernel(const float* __restrict__ probs,
                                                   float* __restrict__ out) {
    int e = blockIdx.x;
    int tid = threadIdx.x;
    float s = 0.f;
    for (int t = tid; t < NTOK; t += 256) s += probs[t * EE + e];
    #pragma unroll
    for (int o = 32; o; o >>= 1) s += __shfl_down(s, o);
    __shared__ float red[4];
    if ((tid & 63) == 0) red[tid >> 6] = s;
    __syncthreads();
    if (tid == 0) out[e] = (red[0] + red[1] + red[2] + red[3]) * (1.f / NTOK);
}

// ---------------- final: out += sum over 2 positions x SPL splits ----------------
__global__ __launch_bounds__(256) void finaladd_kernel(float* __restrict__ out,
                                                       const short* __restrict__ pair_part,
                                                       const int* __restrict__ tok_pos) {
    int t = blockIdx.x;
    int d = threadIdx.x * 4;
    float4 a = *(const float4*)&out[(size_t)t * DD + d];
    #pragma unroll
    for (int sl = 0; sl < 2; sl++) {
        int pos = tok_pos[2 * t + sl];
        #pragma unroll
        for (int s = 0; s < SPL; s++) {
            short4 v = *(const short4*)&pair_part[((size_t)s * CAP + pos) * DD + d];
            a.x += b2f(v.x); a.y += b2f(v.y); a.z += b2f(v.z); a.w += b2f(v.w);
        }
    }
    *(float4*)&out[(size_t)t * DD + d] = a;
}

extern "C" void kernel_launch(void* const* d_in, const int* in_sizes, int n_in,
                              void* d_out, int out_size, void* d_ws, size_t ws_size,
                              hipStream_t stream) {
    const float* x          = (const float*)d_in[0];
    const float* text_state = (const float*)d_in[1];
    const float* ln1_s      = (const float*)d_in[2];
    const float* ln1_b      = (const float*)d_in[3];
    const float* w_qkv      = (const float*)d_in[4];
    const float* b_qkv      = (const float*)d_in[5];
    const float* w_o        = (const float*)d_in[6];
    const float* b_o        = (const float*)d_in[7];
    const float* rel_bias   = (const float*)d_in[8];
    const float* ln2_s      = (const float*)d_in[9];
    const float* ln2_b      = (const float*)d_in[10];
    const float* w_txt      = (const float*)d_in[11];
    const float* b_txt      = (const float*)d_in[12];
    const float* w_r        = (const float*)d_in[13];
    const float* b_r        = (const float*)d_in[14];
    const float* w1         = (const float*)d_in[15];
    const float* b1         = (const float*)d_in[16];
    const float* w2         = (const float*)d_in[17];
    const float* b2         = (const float*)d_in[18];

    float* out = (float*)d_out;   // [NTOK*D] then [E] diag

    // ---- workspace layout ----
    char* p = (char*)d_ws;
    auto alloc = [&](size_t bytes) { char* r = p; p += (bytes + 255) & ~(size_t)255; return r; };
    short* h1b      = (short*)alloc((size_t)NTOK * DD * 2);
    short* Qb       = (short*)alloc((size_t)NTOK * DD * 2);
    short* Kb       = (short*)alloc((size_t)NTOK * DD * 2);
    short* Vb       = (short*)alloc((size_t)NTOK * DD * 2);
    short* VTb      = (short*)alloc((size_t)NTOK * DD * 2);
    // region1: S (f32 33.5MB) -> later Ag(6.3MB)+hid(25.2MB)
    char*  region1  = alloc((size_t)BB * HH * TT * TT * 4);
    // region2: P (bf16 16.8MB) -> later pair_part (SPL x CAP x DD bf16 = 12.6MB)
    char*  region2  = alloc((size_t)BB * HH * TT * TT * 2);
    short* ctxb     = (short*)alloc((size_t)NTOK * DD * 2);
    float* h2       = (float*)alloc((size_t)NTOK * DD * 4);
    float* txt      = (float*)alloc((size_t)BB * DD * 4);
    float* probs    = (float*)alloc((size_t)NTOK * EE * 4);
    float* gates    = (float*)alloc((size_t)NTOK * EE * 4);
    float* pair_gate= (float*)alloc((size_t)CAP * 4);
    int*   counts   = (int*)alloc(8 * 4);
    int*   fill     = (int*)alloc(8 * 4);
    int*   offs     = (int*)alloc(8 * 4);
    int*   tok_pos  = (int*)alloc((size_t)NTOK * 2 * 4);
    short* wqkvT    = (short*)alloc((size_t)3 * DD * DD * 2);        // [3D][D]
    short* woT      = (short*)alloc((size_t)DD * DD * 2);            // [D][D]
    short* w1T      = (short*)alloc((size_t)EE * FF * DD * 2);       // [E][F][D]
    short* w2T      = (short*)alloc((size_t)EE * DD * FF * 2);       // [E][D][F]

    float* S         = (float*)region1;
    short* P         = (short*)region2;
    short* Ag        = (short*)region1;                              // after attn
    short* hid       = (short*)(region1 + (((size_t)CAP * DD * 2 + 255) & ~(size_t)255));
    short* pair_part = (short*)region2;                              // after attn

    // ---- weight prep ----
    transpose_cast<<<dim3(3 * DD / 64, DD / 64, 1), 256, 0, stream>>>(w_qkv, wqkvT, DD, 3 * DD);
    transpose_cast<<<dim3(DD / 64, DD / 64, 1), 256, 0, stream>>>(w_o, woT, DD, DD);
    transpose_cast<<<dim3(FF / 64, DD / 64, EE), 256, 0, stream>>>(w1, w1T, DD, FF);
    transpose_cast<<<dim3(DD / 64, FF / 64, EE), 256, 0, stream>>>(w2, w2T, FF, DD);

    // ---- 1. LN1 (bf16 out) ----
    ln_kernel<1><<<NTOK, 256, 0, stream>>>(x, ln1_s, ln1_b, h1b);
    // ---- 2. QKV GEMM -> bf16 head-major Q/K/V ----
    qkv_mfma<<<dim3(3 * DD / 128, NTOK / 64), 256, 0, stream>>>(h1b, wqkvT, b_qkv, Qb, Kb, Vb);
    // ---- 3. V transpose per (b,h) ----
    v_transpose<<<dim3(TT / 32, DHH / 32, BB * HH), 256, 0, stream>>>(Vb, VTb);
    // ---- 4. scores ----
    scores_mfma<<<dim3(TT / 128, TT / 64, BB * HH), 256, 0, stream>>>(Qb, Kb, S);
    // ---- 5. softmax (scale + rel bias folded) ----
    softmax_kernel<<<BB * HH * TT / 4, 256, 0, stream>>>(S, rel_bias, P);
    // ---- 6. ctx = P @ V^T ----
    pv_mfma<<<dim3(1, TT / 64, BB * HH), 256, 0, stream>>>(P, VTb, ctxb);
    // ---- 7. x1 = x + ctx @ w_o + b_o -> out ----
    gemm64_res_mfma<<<dim3(DD / 64, NTOK / 64), 256, 0, stream>>>(ctxb, woT, b_o, x, out, DD, DD);
    // ---- 8. LN2 (f32 out) ----
    ln_kernel<0><<<NTOK, 256, 0, stream>>>(out, ln2_s, ln2_b, h2);
    // ---- 9. text projection ----
    txt_kernel<<<dim3(DD / 32, BB), 256, 0, stream>>>(text_state, w_txt, b_txt, txt);
    // ---- 10. zero scratch ----
    hipMemsetAsync(counts, 0, 8 * 4, stream);
    hipMemsetAsync(fill, 0, 8 * 4, stream);
    hipMemsetAsync(Ag, 0, (size_t)CAP * DD * 2, stream);
    // ---- 11. router ----
    router_kernel<<<NTOK, 256, 0, stream>>>(h2, txt, w_r, b_r, probs, gates, counts);
    // ---- 12. aligned offsets ----
    offs_kernel<<<1, 64, 0, stream>>>(counts, offs);
    // ---- 13. scatter ----
    scatter_kernel<<<NTOK / 256, 256, 0, stream>>>(gates, offs, fill, tok_pos, pair_gate);
    // ---- 14. gather rows into Ag (bf16) ----
    gather_tokens<<<NTOK * 2, 256, 0, stream>>>(h2, tok_pos, Ag);
    // ---- 15. diag ----
    diag_kernel<<<EE, 256, 0, stream>>>(probs, out + (size_t)NTOK * DD);
    // ---- 16. MoE GEMM1 (128x128) ----
    moe_gemm1_mfma<<<dim3(FF / 128, EE * 16), 256, 0, stream>>>(Ag, w1T, b1, counts, offs, hid);
    // ---- 17. MoE GEMM2 (128x128, split-K) ----
    moe_gemm2_mfma<<<dim3(DD / 128, EE * 16, SPL), 256, 0, stream>>>(hid, w2T, b2, pair_gate, counts, offs, pair_part);
    // ---- 18. final add (sums splits) ----
    finaladd_kernel<<<NTOK, 256, 0, stream>>>(out, pair_part, tok_pos);
}